// Round 4
// baseline (1100.866 us; speedup 1.0000x reference)
//
#include <hip/hip_runtime.h>
#include <math.h>

#define CONVD 192
#define NC 128
#define PW 32
#define LOG2E 1.4426950408889634f
#define LN2f  0.69314718055994531f

// per-dir workspace offsets (floats). Transposed planar layouts [d][B*L].
#define OFF_Z     0u          // z_gT   [8][64][8192]
#define OFF_DT    4194304u    // dt_gT  [8][16][8192]
#define OFF_XH    5242880u    // xh_gT  [8][64][8192]
#define OFF_B     9437184u    // B_gT   [8][64][8192]
#define OFF_C     13631488u   // C_gT   [8][64][8192]
#define OFF_CT2   17825792u   // ct2    [8][16][8192]
#define OFF_DST   18874368u   // Dst    [8*16][128][256]
#define OFF_CHA   23068672u   // chA    [8*16][128]
#define OFF_YS    23085056u   // ys     [8][8192][16]
#define OFF_PART  24133632u   // partials [1024][32]
#define PD        24166400u

// quad-XOR swizzle for [64][64] col-major LDS tiles (row m, col t)
#define XSW(m, t)   ((m) * 64 + (((((t) >> 2) ^ ((m) & 15)) & 15) << 2) + ((t) & 3))
#define XSW4(m, tq) ((m) * 64 + ((((tq) ^ ((m) & 15)) & 15) << 2))

__device__ __forceinline__ float fast_silu(float x) {
    float e = __builtin_amdgcn_exp2f(-x * LOG2E);
    return x * __builtin_amdgcn_rcpf(1.f + e);
}
__device__ __forceinline__ float fast_softplus(float x) {
    if (x > 20.f) return x;
    float e = __builtin_amdgcn_exp2f(x * LOG2E);
    return LN2f * __builtin_amdgcn_logf(1.f + e);
}

template<int CTRL>
__device__ __forceinline__ float dpp_ror_add(float x) {
    int yi = __builtin_amdgcn_update_dpp(0, __float_as_int(x), CTRL, 0xf, 0xf, false);
    return x + __int_as_float(yi);
}
__device__ __forceinline__ float rowsum16(float x) {
    x = dpp_ror_add<0x128>(x);
    x = dpp_ror_add<0x124>(x);
    x = dpp_ror_add<0x122>(x);
    x = dpp_ror_add<0x121>(x);
    return x;
}

// ---------------------------------------------------------------------------
// K_FRONT: wave-per-column-group, lane-per-position.
// proj (reg u, scalar weights) + conv (shfl shift) + silu -> transposed global
// stores; fused per-chunk scan + Dst delta matmul.
// grid (128 ck, 8 b, nz), 512 threads.
// ---------------------------------------------------------------------------
__global__ __launch_bounds__(512, 6) void k_front(
    const float* __restrict__ x, const float* __restrict__ Win,
    const float* __restrict__ convw, const float* __restrict__ convb,
    const float* __restrict__ dtb, const float* __restrict__ A_log,
    float* __restrict__ ws, int dir0, int dslm)
{
    __shared__ float u_s[67 * 17];
    __shared__ float xh_c[4096];   // [hp][t] swizzled; becomes wx
    __shared__ float Bs[4096];     // [n][t] swizzled
    __shared__ float dts[16 * 66];
    __shared__ float wbuf[16 * 66];
    const int tid = threadIdx.x;
    const int ck = blockIdx.x;
    const int b = blockIdx.y;
    const int dir = dir0 + blockIdx.z;
    float* base = ws + (size_t)(dslm * blockIdx.z) * PD;
    float* z_g  = base + OFF_Z;
    float* dt_g = base + OFF_DT;
    float* xh_g = base + OFF_XH;
    float* B_g  = base + OFF_B;
    float* C_g  = base + OFF_C;
    float* ct2  = base + OFF_CT2;
    float* Dst  = base + OFF_DST;
    float* chA  = base + OFF_CHA;
    const int l0 = ck * 64;

    // stage u (67 rows with 3-halo, zero for l<0)
    for (int i = tid; i < 67 * 16; i += 512) {
        int pos = i >> 4, c = i & 15;
        int l = l0 + pos - 3;
        float v = 0.f;
        if (l >= 0) {
            if (dir == 0) {
                v = x[(b * 16 + c) * 8192 + l];
            } else if (dir == 1) {
                int h = l >> 9, w = (l >> 5) & 15, d = l & 31;
                v = x[(((b * 16 + c) * 32 + d) * 16 + h) * 16 + w];
            } else {
                int w = l >> 9, d = (l >> 4) & 31, h = l & 15;
                v = x[(((b * 16 + c) * 32 + d) * 16 + h) * 16 + w];
            }
        }
        u_s[pos * 17 + c] = v;
    }
    __syncthreads();

    const int lane = tid & 63;
    const int wv = __builtin_amdgcn_readfirstlane(tid >> 6);

    float u[16], uh[16];
    {
        const float* ur = &u_s[(lane + 3) * 17];
        #pragma unroll
        for (int k = 0; k < 16; k++) u[k] = ur[k];
        const float* uhr = &u_s[(lane < 3 ? lane : 0) * 17];
        #pragma unroll
        for (int k = 0; k < 16; k++) uh[k] = uhr[k];
    }

    for (int i = 0; i < 34; i++) {
        const int col = wv * 34 + i;
        const float* wp = Win + (size_t)(dir * 272 + col) * 16;
        float acc = 0.f, hacc = 0.f;
        #pragma unroll
        for (int k = 0; k < 16; k++) {
            acc += u[k] * wp[k];
            hacc += uh[k] * wp[k];
        }
        if (col < 64) {
            z_g[((size_t)(b * 64 + col)) * 8192 + l0 + lane] = acc;
        } else if (col < 256) {
            const int ch = col - 64;
            float v1 = __shfl_up(acc, 1);
            float v2 = __shfl_up(acc, 2);
            float v3 = __shfl_up(acc, 3);
            float h0 = __shfl(hacc, 0);
            float h1 = __shfl(hacc, 1);
            float h2 = __shfl(hacc, 2);
            // value at position t-k (halo rows: 0 -> l0-3, 1 -> l0-2, 2 -> l0-1)
            float m1 = (lane >= 1) ? v1 : h2;
            float m2 = (lane >= 2) ? v2 : ((lane == 0) ? h1 : h2);
            float m3 = (lane >= 3) ? v3 : ((lane == 0) ? h0 : ((lane == 1) ? h1 : h2));
            const float* cwp = convw + (size_t)(dir * CONVD + ch) * 4;
            float conv = convb[dir * CONVD + ch]
                       + cwp[0] * m3 + cwp[1] * m2 + cwp[2] * m1 + cwp[3] * acc;
            float xv = fast_silu(conv);
            if (ch < 64) {
                xh_g[((size_t)(b * 64 + ch)) * 8192 + l0 + lane] = xv;
                xh_c[XSW(ch, lane)] = xv;
            } else if (ch < 128) {
                B_g[((size_t)(b * 64 + ch - 64)) * 8192 + l0 + lane] = xv;
                Bs[XSW(ch - 64, lane)] = xv;
            } else {
                C_g[((size_t)(b * 64 + ch - 128)) * 8192 + l0 + lane] = xv;
            }
        } else {
            const int h = col - 256;
            float dv = fast_softplus(acc + dtb[dir * 16 + h]);
            dt_g[((size_t)(b * 16 + h)) * 8192 + l0 + lane] = dv;
            dts[h * 66 + lane] = dv;
        }
    }
    __syncthreads();

    // per-head cumulative log2-decay scan (2 heads per wave)
    for (int h = wv; h < 16; h += 8) {
        float A2 = -expf(A_log[dir * 16 + h]) * LOG2E;
        float dtv = dts[h * 66 + lane];
        float v = dtv * A2;
        #pragma unroll
        for (int off = 1; off < 64; off <<= 1) {
            float o = __shfl_up(v, off, 64);
            if (lane >= off) v += o;
        }
        float tot = __shfl(v, 63, 64);
        ct2[((size_t)(b * 16 + h)) * 8192 + l0 + lane] = v;
        wbuf[h * 66 + lane] = __builtin_amdgcn_exp2f(tot - v) * dtv;
        if (lane == 63) chA[(b * 16 + h) * 128 + ck] = __builtin_amdgcn_exp2f(tot);
    }
    __syncthreads();

    // wx[hp][t] = wbuf[h][t] * xh[hp][t]
    for (int j = tid; j < 4096; j += 512) {
        int hp = j >> 6, t = j & 63;
        xh_c[XSW(hp, t)] *= wbuf[(hp >> 2) * 66 + t];
    }
    __syncthreads();

    // Dst[hp][n] = sum_t wx[hp][t] * B[n][t]
    if (tid < 256) {
        const int hp4 = tid >> 4, n4 = tid & 15;
        float a[4][4] = {};
        for (int tq = 0; tq < 16; tq++) {
            float4 xv[4], bv[4];
            #pragma unroll
            for (int i2 = 0; i2 < 4; i2++) {
                int m = 4 * hp4 + i2;
                xv[i2] = *(const float4*)&xh_c[XSW4(m, tq)];
                int mb = 4 * n4 + i2;
                bv[i2] = *(const float4*)&Bs[XSW4(mb, tq)];
            }
            #pragma unroll
            for (int i2 = 0; i2 < 4; i2++)
                #pragma unroll
                for (int j2 = 0; j2 < 4; j2++)
                    a[i2][j2] += xv[i2].x * bv[j2].x + xv[i2].y * bv[j2].y
                               + xv[i2].z * bv[j2].z + xv[i2].w * bv[j2].w;
        }
        #pragma unroll
        for (int i2 = 0; i2 < 4; i2++) {
            int hp = 4 * hp4 + i2;
            int h = hp >> 2, p = hp & 3;
            *(float4*)(Dst + ((size_t)((b * 16 + h) * 128 + ck)) * 256 + p * 64 + 4 * n4) =
                make_float4(a[i2][0], a[i2][1], a[i2][2], a[i2][3]);
        }
    }
}

// ---------------------------------------------------------------------------
// K_SCAN: inter-chunk scan (sequential over 128 chunks), in place.
// ---------------------------------------------------------------------------
__global__ __launch_bounds__(256) void k_chunk_scan(
    float* __restrict__ ws, int dslm)
{
    float* base = ws + (size_t)(dslm * blockIdx.z) * PD;
    float* Dst = base + OFF_DST;
    const float* chA = base + OFF_CHA;
    const int bh = blockIdx.x;
    const int tid = threadIdx.x;
    float S = 0.f;
    for (int k0 = 0; k0 < NC; k0 += 8) {
        float d[8], av[8];
        #pragma unroll
        for (int j = 0; j < 8; j++) {
            d[j] = Dst[((size_t)(bh * 128 + k0 + j)) * 256 + tid];
            av[j] = chA[bh * 128 + k0 + j];
        }
        #pragma unroll
        for (int j = 0; j < 8; j++) {
            Dst[((size_t)(bh * 128 + k0 + j)) * 256 + tid] = S;
            S = av[j] * S + d[j];
        }
    }
}

// ---------------------------------------------------------------------------
// K_OUT_EPI: chunk output + epilogue (gate/RMSNorm/out-proj) + BN partials.
// grid (128 ck, 8 b, nz), 256 threads. Thread = (t4 = tid>>4, x4 = tid&15).
// ---------------------------------------------------------------------------
__global__ __launch_bounds__(256, 3) void k_out_epi(
    const float* __restrict__ Dp, const float* __restrict__ normw,
    const float* __restrict__ Wout, float* __restrict__ ws, int dir0, int dslm)
{
    __shared__ float T1[4352];       // phase1: B_c [64][68]; phase2: xh_c swz [64][64]
    __shared__ float T2[4352];       // phase1: C_c [64][68]; phase2: z_c swz
    __shared__ float T3[4160];       // phase1: Sn [64][65]; phase2: dts/ct2/WoutN/Dp
    __shared__ float red[4][34];
    float* base = ws + (size_t)(dslm * blockIdx.z) * PD;
    const float* z_g   = base + OFF_Z;
    const float* dt_g  = base + OFF_DT;
    const float* xh_g  = base + OFF_XH;
    const float* B_g   = base + OFF_B;
    const float* C_g   = base + OFF_C;
    const float* ct2_g = base + OFF_CT2;
    const float* Dst   = base + OFF_DST;
    float* ys          = base + OFF_YS;
    float* partials    = base + OFF_PART;
    const int dir = dir0 + blockIdx.z;
    const int tid = threadIdx.x;
    const int b = blockIdx.y;
    const int ck = blockIdx.x;
    const int l0 = ck * 64;
    const int t4 = tid >> 4, x4 = tid & 15;

    // phase-1 staging: B_c, C_c [n][68]; Sn [hp][65]
    for (int j = tid; j < 1024; j += 256) {
        int n = j >> 4, tq = (j & 15) << 2;
        float4 bv = *(const float4*)(B_g + ((size_t)(b * 64 + n)) * 8192 + l0 + tq);
        float4 cv = *(const float4*)(C_g + ((size_t)(b * 64 + n)) * 8192 + l0 + tq);
        *(float4*)&T1[n * 68 + tq] = bv;
        *(float4*)&T2[n * 68 + tq] = cv;
    }
    for (int j = tid; j < 1024; j += 256) {
        int hp = j >> 4, nq = (j & 15) << 2;
        int h = hp >> 2, p = hp & 3;
        float4 sv = *(const float4*)(Dst + ((size_t)((b * 16 + h) * 128 + ck)) * 256 + p * 64 + nq);
        T3[hp * 65 + nq]     = sv.x;
        T3[hp * 65 + nq + 1] = sv.y;
        T3[hp * 65 + nq + 2] = sv.z;
        T3[hp * 65 + nq + 3] = sv.w;
    }
    __syncthreads();

    // G[t][s] = sum_n C[n][t]B[n][s];  CS[t][hp] = sum_n C[n][t]Sin[hp][n]
    float G_[4][4] = {}, CS_[4][4] = {};
    for (int n = 0; n < 64; n++) {
        float4 cr4 = *(const float4*)&T2[n * 68 + 4 * t4];
        float4 br4 = *(const float4*)&T1[n * 68 + 4 * x4];
        float cr[4] = {cr4.x, cr4.y, cr4.z, cr4.w};
        float br[4] = {br4.x, br4.y, br4.z, br4.w};
        float sn[4];
        #pragma unroll
        for (int q = 0; q < 4; q++) sn[q] = T3[(4 * x4 + q) * 65 + n];
        #pragma unroll
        for (int r = 0; r < 4; r++)
            #pragma unroll
            for (int q = 0; q < 4; q++) {
                G_[r][q] += cr[r] * br[q];
                CS_[r][q] += cr[r] * sn[q];
            }
    }
    __syncthreads();

    // phase-2 staging: xh_c, z_c swizzled; dts/ct2/WoutN/Dps into T3
    float* dts_l = T3;           // [16][65]
    float* ct2_l = T3 + 1040;    // [16][65]
    float* WoN   = T3 + 2080;    // [16][65]
    float* Dps   = T3 + 3120;    // [16]
    for (int j = tid; j < 1024; j += 256) {
        int d = j >> 4, tq = (j & 15) << 2;
        float4 xv = *(const float4*)(xh_g + ((size_t)(b * 64 + d)) * 8192 + l0 + tq);
        float4 zv = *(const float4*)(z_g + ((size_t)(b * 64 + d)) * 8192 + l0 + tq);
        int a0 = XSW4(d, (tq >> 2));
        *(float4*)&T1[a0] = xv;
        *(float4*)&T2[a0] = zv;
    }
    for (int j = tid; j < 1024; j += 256) {
        int h = j >> 6, t = j & 63;
        dts_l[h * 65 + t] = dt_g[((size_t)(b * 16 + h)) * 8192 + l0 + t];
        ct2_l[h * 65 + t] = ct2_g[((size_t)(b * 16 + h)) * 8192 + l0 + t];
        WoN[h * 65 + t] = Wout[dir * 1024 + j] * normw[dir * 64 + t];
    }
    if (tid < 16) Dps[tid] = Dp[dir * 16 + tid];
    __syncthreads();

    const int tbase = 4 * t4;
    float yreg[16];
    #pragma unroll
    for (int h = 0; h < 16; h++) {
        float ctt[4], ect[4];
        #pragma unroll
        for (int r = 0; r < 4; r++) {
            ctt[r] = ct2_l[h * 65 + tbase + r];
            ect[r] = __builtin_amdgcn_exp2f(ctt[r]);
        }
        float acc[4][4] = {};  // [r][p]
        #pragma unroll
        for (int q = 0; q < 4; q++) {
            int s = 4 * x4 + q;
            float cs_ = ct2_l[h * 65 + s];
            float dtq = dts_l[h * 65 + s];
            float xv[4];
            #pragma unroll
            for (int p = 0; p < 4; p++) {
                int m = 4 * h + p;
                xv[p] = T1[m * 64 + ((((x4) ^ (m & 15)) & 15) << 2) + q];
            }
            #pragma unroll
            for (int r = 0; r < 4; r++) {
                float e = __builtin_amdgcn_exp2f(ctt[r] - cs_);
                e = (s <= tbase + r) ? e : 0.f;
                float w = G_[r][q] * e * dtq;
                #pragma unroll
                for (int p = 0; p < 4; p++) acc[r][p] += w * xv[p];
            }
        }
        if (x4 == h) {
            #pragma unroll
            for (int r = 0; r < 4; r++)
                #pragma unroll
                for (int p = 0; p < 4; p++)
                    acc[r][p] += ect[r] * CS_[r][p];
        }
        #pragma unroll
        for (int r = 0; r < 4; r++)
            #pragma unroll
            for (int p = 0; p < 4; p++)
                acc[r][p] = rowsum16(acc[r][p]);
        float outv = acc[0][0];
        #pragma unroll
        for (int r = 0; r < 4; r++)
            #pragma unroll
            for (int p = 0; p < 4; p++)
                if (r || p) outv = (x4 == r * 4 + p) ? acc[r][p] : outv;
        yreg[h] = outv;
    }

    // epilogue: lane holds y[row][4h+p] for h=0..15
    const int row = tbase + (x4 >> 2);
    const int p = x4 & 3;
    float g[16], sumsq = 0.f;
    #pragma unroll
    for (int h = 0; h < 16; h++) {
        int m = 4 * h + p;
        int ax = m * 64 + ((((row >> 2) ^ (m & 15)) & 15) << 2) + (row & 3);
        float xh = T1[ax];
        float zv = T2[ax];
        float val = (yreg[h] + Dps[h] * xh) * fast_silu(zv);
        g[h] = val;
        sumsq += val * val;
    }
    sumsq += __shfl_xor(sumsq, 1);
    sumsq += __shfl_xor(sumsq, 2);
    float rms = rsqrtf(sumsq * (1.f / 64.f) + 1e-5f);

    float oc[16];
    #pragma unroll
    for (int c = 0; c < 16; c++) {
        float a = 0.f;
        #pragma unroll
        for (int h = 0; h < 16; h++) a += g[h] * WoN[c * 65 + 4 * h + p];
        oc[c] = a;
    }
    #pragma unroll
    for (int c = 0; c < 16; c++) {
        oc[c] += __shfl_xor(oc[c], 1);
        oc[c] += __shfl_xor(oc[c], 2);
    }
    // lane p extracts channels 4p..4p+3 (static-index selects)
    float os[4];
    #pragma unroll
    for (int i2 = 0; i2 < 4; i2++) {
        float a0 = (p == 0) ? oc[i2] : oc[4 + i2];
        float a1 = (p == 2) ? oc[8 + i2] : oc[12 + i2];
        os[i2] = (((p & 2) == 0) ? a0 : a1) * rms;
    }
    size_t bl = (size_t)(b * 8192 + l0 + row);
    *(float4*)(ys + bl * 16 + 4 * p) = make_float4(os[0], os[1], os[2], os[3]);

    // BN partials
    float bs[4], bq[4];
    #pragma unroll
    for (int i2 = 0; i2 < 4; i2++) {
        float vv = fmaxf(os[i2], 0.f);
        bs[i2] = vv;
        bq[i2] = vv * vv;
    }
    #pragma unroll
    for (int off = 4; off < 64; off <<= 1) {
        #pragma unroll
        for (int i2 = 0; i2 < 4; i2++) {
            bs[i2] += __shfl_xor(bs[i2], off);
            bq[i2] += __shfl_xor(bq[i2], off);
        }
    }
    const int wlane = tid & 63, wvid = tid >> 6;
    if (wlane < 4) {
        #pragma unroll
        for (int i2 = 0; i2 < 4; i2++) {
            red[wvid][4 * wlane + i2] = bs[i2];
            red[wvid][16 + 4 * wlane + i2] = bq[i2];
        }
    }
    __syncthreads();
    if (tid < 32) {
        float a = red[0][tid] + red[1][tid] + red[2][tid] + red[3][tid];
        partials[((size_t)(b * 128 + ck)) * 32 + tid] = a;
    }
}

// ---------------------------------------------------------------------------
// K_POOL_BN: reduce partials -> BN coefs (redundant per block), then
// BN-apply + linear + maxpool(32). grid (64, 1, nz).
// ---------------------------------------------------------------------------
__global__ __launch_bounds__(256) void k_pool_bn(
    const float* __restrict__ gamma, const float* __restrict__ beta,
    const float* __restrict__ lin_w, const float* __restrict__ lin_b,
    float* __restrict__ ws, float* __restrict__ out, int dir0, int dslm)
{
    float* base = ws + (size_t)(dslm * blockIdx.z) * PD;
    const float* ys = base + OFF_YS;
    const float* partials = base + OFF_PART;
    const int dir = dir0 + blockIdx.z;
    const int tid = threadIdx.x;
    __shared__ float red[8][33];
    __shared__ float cf[18];
    {
        int c = tid & 31, ks = tid >> 5;
        float a = 0.f;
        for (int k = ks * 128; k < ks * 128 + 128; k++) a += partials[k * 32 + c];
        red[ks][c] = a;
    }
    __syncthreads();
    if (tid < 32) {
        float a = 0.f;
        #pragma unroll
        for (int s2 = 1; s2 < 8; s2++) a += red[s2][tid];
        red[0][tid] += a;
    }
    __syncthreads();
    if (tid == 0) {
        float off = lin_b[dir];
        for (int c = 0; c < 16; c++) {
            float mu = red[0][c] * (1.f / 65536.f);
            float var = red[0][16 + c] * (1.f / 65536.f) - mu * mu;
            float inv = rsqrtf(var + 1e-5f);
            float coef = inv * gamma[dir * 16 + c] * lin_w[dir * 16 + c];
            cf[c] = coef;
            off += beta[dir * 16 + c] * lin_w[dir * 16 + c] - mu * coef;
        }
        cf[16] = off;
    }
    __syncthreads();

    const int b = blockIdx.x >> 3;
    const int jg = blockIdx.x & 7;
    const int j = jg * 32 + (tid >> 3);
    const int sub = tid & 7;
    float m = -3.4e38f;
    #pragma unroll
    for (int r = 0; r < 4; r++) {
        int l = j * PW + 8 * r + sub;
        const float* rowp = ys + (size_t)(b * 8192 + l) * 16;
        float sv = cf[16];
        #pragma unroll
        for (int k = 0; k < 4; k++) {
            float4 v4 = *(const float4*)(rowp + 4 * k);
            sv += fmaxf(v4.x, 0.f) * cf[4 * k] + fmaxf(v4.y, 0.f) * cf[4 * k + 1]
                + fmaxf(v4.z, 0.f) * cf[4 * k + 2] + fmaxf(v4.w, 0.f) * cf[4 * k + 3];
        }
        m = fmaxf(m, sv);
    }
    m = fmaxf(m, __shfl_xor(m, 1));
    m = fmaxf(m, __shfl_xor(m, 2));
    m = fmaxf(m, __shfl_xor(m, 4));
    if (sub == 0) out[b * 768 + dir * 256 + j] = m;
}

// ---------------------------------------------------------------------------
extern "C" void kernel_launch(void* const* d_in, const int* in_sizes, int n_in,
                              void* d_out, int out_size, void* d_ws, size_t ws_size,
                              hipStream_t stream) {
    const float* x     = (const float*)d_in[0];
    const float* Win   = (const float*)d_in[1];
    const float* convw = (const float*)d_in[2];
    const float* convb = (const float*)d_in[3];
    const float* dtb   = (const float*)d_in[4];
    const float* Alog  = (const float*)d_in[5];
    const float* Dp    = (const float*)d_in[6];
    const float* normw = (const float*)d_in[7];
    const float* Wout  = (const float*)d_in[8];
    const float* gamma = (const float*)d_in[9];
    const float* beta  = (const float*)d_in[10];
    const float* linw  = (const float*)d_in[11];
    const float* linb  = (const float*)d_in[12];
    float* out = (float*)d_out;
    float* ws = (float*)d_ws;

    const bool batched = ws_size >= (size_t)3 * PD * 4;
    const int nz = batched ? 3 : 1;
    const int dslm = batched ? 1 : 0;
    const int nloop = batched ? 1 : 3;

    for (int d0 = 0; d0 < nloop; ++d0) {
        k_front<<<dim3(128, 8, nz), dim3(512), 0, stream>>>(
            x, Win, convw, convb, dtb, Alog, ws, d0, dslm);
        k_chunk_scan<<<dim3(128, 1, nz), dim3(256), 0, stream>>>(ws, dslm);
        k_out_epi<<<dim3(128, 8, nz), dim3(256), 0, stream>>>(
            Dp, normw, Wout, ws, d0, dslm);
        k_pool_bn<<<dim3(64, 1, nz), dim3(256), 0, stream>>>(
            gamma, beta, linw, linb, ws, out, d0, dslm);
    }
}

// Round 5
// 437.860 us; speedup vs baseline: 2.5142x; 2.5142x over previous
//
#include <hip/hip_runtime.h>
#include <math.h>

#define CONVD 192
#define NC 128
#define PW 32
#define LOG2E 1.4426950408889634f
#define LN2f  0.69314718055994531f

// per-dir workspace offsets (floats)
#define OFF_DST   0u          // Dst  [8*16][128][256]  (delta -> Sin after scan)
#define OFF_CHA   4194304u    // chA  [8*16][128]
#define OFF_YS    4210688u    // ys   [8][8192][16]
#define OFF_PART  5259264u    // partials [1024][32]
#define PD        5292032u    // floats per dir region (21.2 MB)

// XOR-quad swizzle for [64][64] LDS tiles, element (row m, col t)
#define XSW(m, t)   ((m) * 64 + (((((t) >> 2) ^ ((m) & 15)) & 15) << 2) + ((t) & 3))
#define XSW4(m, tq) ((m) * 64 + ((((tq) ^ ((m) & 15)) & 15) << 2))

__device__ __forceinline__ float fast_silu(float x) {
    float e = __builtin_amdgcn_exp2f(-x * LOG2E);
    return x * __builtin_amdgcn_rcpf(1.f + e);
}
__device__ __forceinline__ float fast_softplus(float x) {
    if (x > 20.f) return x;
    float e = __builtin_amdgcn_exp2f(x * LOG2E);
    return LN2f * __builtin_amdgcn_logf(1.f + e);
}

template<int CTRL>
__device__ __forceinline__ float dpp_ror_add(float x) {
    int yi = __builtin_amdgcn_update_dpp(0, __float_as_int(x), CTRL, 0xf, 0xf, false);
    return x + __int_as_float(yi);
}
__device__ __forceinline__ float rowsum16(float x) {
    x = dpp_ror_add<0x128>(x);
    x = dpp_ror_add<0x124>(x);
    x = dpp_ror_add<0x122>(x);
    x = dpp_ror_add<0x121>(x);
    return x;
}

// stage u rows [pos][c] (67 x 16, pad 17) with 3-halo, zeros for l<0
template<int NT>
__device__ __forceinline__ void stage_u(
    const float* __restrict__ x, float* u_s, int b, int l0, int dir, int tid)
{
    for (int i = tid; i < 67 * 16; i += NT) {
        int pos = i >> 4, c = i & 15;
        int l = l0 + pos - 3;
        float v = 0.f;
        if (l >= 0) {
            if (dir == 0) {
                v = x[(b * 16 + c) * 8192 + l];
            } else if (dir == 1) {
                int h = l >> 9, w = (l >> 5) & 15, d = l & 31;
                v = x[(((b * 16 + c) * 32 + d) * 16 + h) * 16 + w];
            } else {
                int w = l >> 9, d = (l >> 4) & 31, h = l & 15;
                v = x[(((b * 16 + c) * 32 + d) * 16 + h) * 16 + w];
            }
        }
        u_s[pos * 17 + c] = v;
    }
}

// ---------------------------------------------------------------------------
// K_DELTA: proj (xh, B, dt only) + conv + silu + scan + chunk state delta.
// Writes ONLY Dst + chA. grid (128 ck, 8 b, nz), 512 threads.
// ---------------------------------------------------------------------------
__global__ __launch_bounds__(512, 6) void k_delta(
    const float* __restrict__ x, const float* __restrict__ Win,
    const float* __restrict__ convw, const float* __restrict__ convb,
    const float* __restrict__ dtb, const float* __restrict__ A_log,
    float* __restrict__ ws, int dir0, int dslm)
{
    __shared__ float u_s[67 * 17];
    __shared__ float xh_c[4096];   // [d][t] swizzled; becomes wx
    __shared__ float Bs[4096];     // [n][t] swizzled
    __shared__ float dts[16 * 65];
    __shared__ float wbuf[16 * 65];
    const int tid = threadIdx.x;
    const int ck = blockIdx.x;
    const int b = blockIdx.y;
    const int dir = dir0 + blockIdx.z;
    float* base = ws + (size_t)(dslm * blockIdx.z) * PD;
    float* Dst = base + OFF_DST;
    float* chA = base + OFF_CHA;
    const int l0 = ck * 64;

    stage_u<512>(x, u_s, b, l0, dir, tid);
    __syncthreads();

    const int lane = tid & 63;
    const int wv = __builtin_amdgcn_readfirstlane(tid >> 6);

    float u[16], uh[16];
    {
        const float* ur = &u_s[(lane + 3) * 17];
        #pragma unroll
        for (int k = 0; k < 16; k++) u[k] = ur[k];
        const float* uhr = &u_s[(lane < 3 ? lane : 0) * 17];
        #pragma unroll
        for (int k = 0; k < 16; k++) uh[k] = uhr[k];
    }

    // 144 cols (xh 64..127, B 128..191, dt 256..271) over 8 waves
    for (int i = 0; i < 18; i++) {
        const int g = wv * 18 + i;
        const int col = (g < 128) ? (64 + g) : (256 + (g - 128));
        const float* wp = Win + (size_t)(dir * 272 + col) * 16;
        float acc = 0.f, hacc = 0.f;
        #pragma unroll
        for (int k = 0; k < 16; k++) {
            acc += u[k] * wp[k];
            hacc += uh[k] * wp[k];
        }
        if (col < 256) {
            const int ch = col - 64;
            float v1 = __shfl_up(acc, 1);
            float v2 = __shfl_up(acc, 2);
            float v3 = __shfl_up(acc, 3);
            float h0 = __shfl(hacc, 0);
            float h1 = __shfl(hacc, 1);
            float h2 = __shfl(hacc, 2);
            float m1 = (lane >= 1) ? v1 : h2;
            float m2 = (lane >= 2) ? v2 : ((lane == 0) ? h1 : h2);
            float m3 = (lane >= 3) ? v3 : ((lane == 0) ? h0 : ((lane == 1) ? h1 : h2));
            const float* cwp = convw + (size_t)(dir * CONVD + ch) * 4;
            float conv = convb[dir * CONVD + ch]
                       + cwp[0] * m3 + cwp[1] * m2 + cwp[2] * m1 + cwp[3] * acc;
            float xv = fast_silu(conv);
            if (ch < 64) xh_c[XSW(ch, lane)] = xv;
            else         Bs[XSW(ch - 64, lane)] = xv;
        } else {
            const int h = col - 256;
            dts[h * 65 + lane] = fast_softplus(acc + dtb[dir * 16 + h]);
        }
    }
    __syncthreads();

    // per-head cumulative log2-decay scan (2 heads per wave)
    for (int h = wv; h < 16; h += 8) {
        float A2 = -expf(A_log[dir * 16 + h]) * LOG2E;
        float dtv = dts[h * 65 + lane];
        float v = dtv * A2;
        #pragma unroll
        for (int off = 1; off < 64; off <<= 1) {
            float o = __shfl_up(v, off, 64);
            if (lane >= off) v += o;
        }
        float tot = __shfl(v, 63, 64);
        wbuf[h * 65 + lane] = __builtin_amdgcn_exp2f(tot - v) * dtv;
        if (lane == 63) chA[(b * 16 + h) * 128 + ck] = __builtin_amdgcn_exp2f(tot);
    }
    __syncthreads();

    // wx[d][t] = wbuf[h][t] * xh[d][t]
    for (int j = tid; j < 4096; j += 512) {
        int hp = j >> 6, t = j & 63;
        xh_c[XSW(hp, t)] *= wbuf[(hp >> 2) * 65 + t];
    }
    __syncthreads();

    // Dst[hp][n] = sum_t wx[hp][t] * B[n][t]
    if (tid < 256) {
        const int hp4 = tid >> 4, n4 = tid & 15;
        float a[4][4] = {};
        for (int tq = 0; tq < 16; tq++) {
            float4 xv[4], bv[4];
            #pragma unroll
            for (int i2 = 0; i2 < 4; i2++) {
                xv[i2] = *(const float4*)&xh_c[XSW4(4 * hp4 + i2, tq)];
                bv[i2] = *(const float4*)&Bs[XSW4(4 * n4 + i2, tq)];
            }
            #pragma unroll
            for (int i2 = 0; i2 < 4; i2++)
                #pragma unroll
                for (int j2 = 0; j2 < 4; j2++)
                    a[i2][j2] += xv[i2].x * bv[j2].x + xv[i2].y * bv[j2].y
                               + xv[i2].z * bv[j2].z + xv[i2].w * bv[j2].w;
        }
        #pragma unroll
        for (int i2 = 0; i2 < 4; i2++) {
            int hp = 4 * hp4 + i2;
            int h = hp >> 2, p = hp & 3;
            *(float4*)(Dst + ((size_t)((b * 16 + h) * 128 + ck)) * 256 + p * 64 + 4 * n4) =
                make_float4(a[i2][0], a[i2][1], a[i2][2], a[i2][3]);
        }
    }
}

// ---------------------------------------------------------------------------
// K_SCAN: inter-chunk scan, in place. grid (512, 1, nz) x 64 threads:
// block = (bh = bx>>2, state quarter = bx&3).
// ---------------------------------------------------------------------------
__global__ __launch_bounds__(64) void k_chunk_scan(
    float* __restrict__ ws, int dslm)
{
    float* base = ws + (size_t)(dslm * blockIdx.z) * PD;
    float* Dst = base + OFF_DST;
    const float* chA = base + OFF_CHA;
    const int bh = blockIdx.x >> 2;
    const int elem = (blockIdx.x & 3) * 64 + threadIdx.x;
    float S = 0.f;
    for (int k0 = 0; k0 < NC; k0 += 8) {
        float d[8], av[8];
        #pragma unroll
        for (int j = 0; j < 8; j++) {
            d[j] = Dst[((size_t)(bh * 128 + k0 + j)) * 256 + elem];
            av[j] = chA[bh * 128 + k0 + j];
        }
        #pragma unroll
        for (int j = 0; j < 8; j++) {
            Dst[((size_t)(bh * 128 + k0 + j)) * 256 + elem] = S;
            S = av[j] * S + d[j];
        }
    }
}

// ---------------------------------------------------------------------------
// K_OUT_EPI: full recompute of front (proj+conv+silu+scan) from x, then
// chunk output + epilogue + BN partials. grid (128 ck, 8 b, nz), 256 thr.
// ---------------------------------------------------------------------------
__global__ __launch_bounds__(256, 2) void k_out_epi(
    const float* __restrict__ x, const float* __restrict__ Win,
    const float* __restrict__ convw, const float* __restrict__ convb,
    const float* __restrict__ dtb, const float* __restrict__ A_log,
    const float* __restrict__ Dp, const float* __restrict__ normw,
    const float* __restrict__ Wout, float* __restrict__ ws, int dir0, int dslm)
{
    __shared__ float SinT[64 * 68];   // [n][hp]
    __shared__ float xh_c[4096];      // [d][t] swizzled
    __shared__ float Bz[4096];        // B [n][t] swz, then z [d][t] swz
    __shared__ float Cc[4096];        // C [n][t] swz
    __shared__ float uW[67 * 17];     // u_s, then WoN [16][65]
    __shared__ float dts[16 * 65];
    __shared__ float ct2l[16 * 65];
    __shared__ float Dps[16];
    __shared__ float red[4][34];
    float* base = ws + (size_t)(dslm * blockIdx.z) * PD;
    const float* Dst = base + OFF_DST;
    float* ys        = base + OFF_YS;
    float* partials  = base + OFF_PART;
    const int dir = dir0 + blockIdx.z;
    const int tid = threadIdx.x;
    const int b = blockIdx.y;
    const int ck = blockIdx.x;
    const int l0 = ck * 64;
    const int t4 = tid >> 4, x4 = tid & 15;
    const int lane = tid & 63;
    const int wv = __builtin_amdgcn_readfirstlane(tid >> 6);

    // phase A: stage u + SinT + Dps
    stage_u<256>(x, uW, b, l0, dir, tid);
    for (int j = tid; j < 1024; j += 256) {
        int hp = j >> 4, n4 = (j & 15) << 2;
        int h = hp >> 2, p = hp & 3;
        float4 sv = *(const float4*)(Dst + ((size_t)((b * 16 + h) * 128 + ck)) * 256 + p * 64 + n4);
        SinT[(n4 + 0) * 68 + hp] = sv.x;
        SinT[(n4 + 1) * 68 + hp] = sv.y;
        SinT[(n4 + 2) * 68 + hp] = sv.z;
        SinT[(n4 + 3) * 68 + hp] = sv.w;
    }
    if (tid < 16) Dps[tid] = Dp[dir * 16 + tid];
    __syncthreads();

    float u[16], uh[16];
    {
        const float* ur = &uW[(lane + 3) * 17];
        #pragma unroll
        for (int k = 0; k < 16; k++) u[k] = ur[k];
        const float* uhr = &uW[(lane < 3 ? lane : 0) * 17];
        #pragma unroll
        for (int k = 0; k < 16; k++) uh[k] = uhr[k];
    }

    // phase B: proj cols 64..271 (xh, B, C, dt); 4 waves x 52 cols
    for (int i = 0; i < 52; i++) {
        const int col = 64 + wv * 52 + i;
        const float* wp = Win + (size_t)(dir * 272 + col) * 16;
        float acc = 0.f, hacc = 0.f;
        #pragma unroll
        for (int k = 0; k < 16; k++) {
            acc += u[k] * wp[k];
            hacc += uh[k] * wp[k];
        }
        if (col < 256) {
            const int ch = col - 64;
            float v1 = __shfl_up(acc, 1);
            float v2 = __shfl_up(acc, 2);
            float v3 = __shfl_up(acc, 3);
            float h0 = __shfl(hacc, 0);
            float h1 = __shfl(hacc, 1);
            float h2 = __shfl(hacc, 2);
            float m1 = (lane >= 1) ? v1 : h2;
            float m2 = (lane >= 2) ? v2 : ((lane == 0) ? h1 : h2);
            float m3 = (lane >= 3) ? v3 : ((lane == 0) ? h0 : ((lane == 1) ? h1 : h2));
            const float* cwp = convw + (size_t)(dir * CONVD + ch) * 4;
            float conv = convb[dir * CONVD + ch]
                       + cwp[0] * m3 + cwp[1] * m2 + cwp[2] * m1 + cwp[3] * acc;
            float xv = fast_silu(conv);
            if (ch < 64)       xh_c[XSW(ch, lane)] = xv;
            else if (ch < 128) Bz[XSW(ch - 64, lane)] = xv;
            else               Cc[XSW(ch - 128, lane)] = xv;
        } else {
            const int h = col - 256;
            dts[h * 65 + lane] = fast_softplus(acc + dtb[dir * 16 + h]);
        }
    }
    __syncthreads();

    // phase C: scan -> ct2 (LDS only); 4 waves x 4 heads
    for (int h = wv; h < 16; h += 4) {
        float A2 = -expf(A_log[dir * 16 + h]) * LOG2E;
        float dtv = dts[h * 65 + lane];
        float v = dtv * A2;
        #pragma unroll
        for (int off = 1; off < 64; off <<= 1) {
            float o = __shfl_up(v, off, 64);
            if (lane >= off) v += o;
        }
        ct2l[h * 65 + lane] = v;
    }
    __syncthreads();

    // phase D: G[t][s] = sum_n C[n][t]B[n][s]; CS[t][hp] = sum_n C[n][t]Sin[hp][n]
    float G_[4][4] = {}, CS_[4][4] = {};
    for (int n = 0; n < 64; n++) {
        float4 cr4 = *(const float4*)&Cc[XSW4(n, t4)];
        float4 br4 = *(const float4*)&Bz[XSW4(n, x4)];
        float cr[4] = {cr4.x, cr4.y, cr4.z, cr4.w};
        float br[4] = {br4.x, br4.y, br4.z, br4.w};
        float sn[4];
        #pragma unroll
        for (int q = 0; q < 4; q++) sn[q] = SinT[n * 68 + 4 * x4 + q];
        #pragma unroll
        for (int r = 0; r < 4; r++)
            #pragma unroll
            for (int q = 0; q < 4; q++) {
                G_[r][q] += cr[r] * br[q];
                CS_[r][q] += cr[r] * sn[q];
            }
    }
    __syncthreads();  // B, SinT dead

    // phase E: proj z (cols 0..63) into Bz slot; WoN into uW slot
    for (int i = 0; i < 16; i++) {
        const int col = wv * 16 + i;
        const float* wp = Win + (size_t)(dir * 272 + col) * 16;
        float acc = 0.f;
        #pragma unroll
        for (int k = 0; k < 16; k++) acc += u[k] * wp[k];
        Bz[XSW(col, lane)] = acc;
    }
    __syncthreads();  // u_s (uW) dead only after z-proj reads of u regs; safe
    for (int j = tid; j < 1024; j += 256) {
        int c = j >> 6, d = j & 63;
        uW[c * 65 + d] = Wout[dir * 1024 + j] * normw[dir * 64 + d];
    }
    __syncthreads();

    // phase F: per-head y
    const int tbase = 4 * t4;
    float g[16];
    #pragma unroll 1
    for (int h = 0; h < 16; h++) {
        float ctt[4], ect[4];
        #pragma unroll
        for (int r = 0; r < 4; r++) {
            ctt[r] = ct2l[h * 65 + tbase + r];
            ect[r] = __builtin_amdgcn_exp2f(ctt[r]);
        }
        float acc[4][4] = {};  // [r][p]
        #pragma unroll
        for (int q = 0; q < 4; q++) {
            int s = 4 * x4 + q;
            float cs_ = ct2l[h * 65 + s];
            float dtq = dts[h * 65 + s];
            float xv[4];
            #pragma unroll
            for (int p = 0; p < 4; p++) {
                int m = 4 * h + p;
                xv[p] = xh_c[m * 64 + (((x4 ^ (m & 15)) & 15) << 2) + q];
            }
            #pragma unroll
            for (int r = 0; r < 4; r++) {
                float e = __builtin_amdgcn_exp2f(ctt[r] - cs_);
                e = (s <= tbase + r) ? e : 0.f;
                float w = G_[r][q] * e * dtq;
                #pragma unroll
                for (int p = 0; p < 4; p++) acc[r][p] += w * xv[p];
            }
        }
        if (x4 == h) {
            #pragma unroll
            for (int r = 0; r < 4; r++)
                #pragma unroll
                for (int p = 0; p < 4; p++)
                    acc[r][p] += ect[r] * CS_[r][p];
        }
        #pragma unroll
        for (int r = 0; r < 4; r++)
            #pragma unroll
            for (int p = 0; p < 4; p++)
                acc[r][p] = rowsum16(acc[r][p]);
        float outv = acc[0][0];
        #pragma unroll
        for (int r = 0; r < 4; r++)
            #pragma unroll
            for (int p = 0; p < 4; p++)
                if (r || p) outv = (x4 == r * 4 + p) ? acc[r][p] : outv;
        g[h] = outv;  // lane x4 holds y[tbase + (x4>>2)][4h + (x4&3)]
    }

    // phase G: epilogue. lane = (row = tbase + x4>>2, p = x4&3)
    const int row = tbase + (x4 >> 2);
    const int p = x4 & 3;
    float sumsq = 0.f;
    #pragma unroll
    for (int h = 0; h < 16; h++) {
        int m = 4 * h + p;
        int ax = m * 64 + ((((row >> 2) ^ (m & 15)) & 15) << 2) + (row & 3);
        float xh = xh_c[ax];
        float zv = Bz[ax];
        float val = (g[h] + Dps[h] * xh) * fast_silu(zv);
        g[h] = val;
        sumsq += val * val;
    }
    sumsq += __shfl_xor(sumsq, 1);
    sumsq += __shfl_xor(sumsq, 2);
    float rms = rsqrtf(sumsq * (1.f / 64.f) + 1e-5f);

    float oc[16];
    #pragma unroll
    for (int c = 0; c < 16; c++) {
        float a = 0.f;
        #pragma unroll
        for (int h = 0; h < 16; h++) a += g[h] * uW[c * 65 + 4 * h + p];
        oc[c] = a;
    }
    #pragma unroll
    for (int c = 0; c < 16; c++) {
        oc[c] += __shfl_xor(oc[c], 1);
        oc[c] += __shfl_xor(oc[c], 2);
    }
    float os[4];
    #pragma unroll
    for (int i2 = 0; i2 < 4; i2++) {
        float a0 = (p == 0) ? oc[i2] : oc[4 + i2];
        float a1 = (p == 2) ? oc[8 + i2] : oc[12 + i2];
        os[i2] = (((p & 2) == 0) ? a0 : a1) * rms;
    }
    size_t bl = (size_t)(b * 8192 + l0 + row);
    *(float4*)(ys + bl * 16 + 4 * p) = make_float4(os[0], os[1], os[2], os[3]);

    // BN partials
    float bs[4], bq[4];
    #pragma unroll
    for (int i2 = 0; i2 < 4; i2++) {
        float vv = fmaxf(os[i2], 0.f);
        bs[i2] = vv;
        bq[i2] = vv * vv;
    }
    #pragma unroll
    for (int off = 4; off < 64; off <<= 1) {
        #pragma unroll
        for (int i2 = 0; i2 < 4; i2++) {
            bs[i2] += __shfl_xor(bs[i2], off);
            bq[i2] += __shfl_xor(bq[i2], off);
        }
    }
    const int wlane = tid & 63, wvid = tid >> 6;
    if (wlane < 4) {
        #pragma unroll
        for (int i2 = 0; i2 < 4; i2++) {
            red[wvid][4 * wlane + i2] = bs[i2];
            red[wvid][16 + 4 * wlane + i2] = bq[i2];
        }
    }
    __syncthreads();
    if (tid < 32) {
        float a = red[0][tid] + red[1][tid] + red[2][tid] + red[3][tid];
        partials[((size_t)(b * 128 + ck)) * 32 + tid] = a;
    }
}

// ---------------------------------------------------------------------------
// K_POOL_BN: reduce partials -> BN coefs, then BN + linear + maxpool(32).
// ---------------------------------------------------------------------------
__global__ __launch_bounds__(256) void k_pool_bn(
    const float* __restrict__ gamma, const float* __restrict__ beta,
    const float* __restrict__ lin_w, const float* __restrict__ lin_b,
    float* __restrict__ ws, float* __restrict__ out, int dir0, int dslm)
{
    float* base = ws + (size_t)(dslm * blockIdx.z) * PD;
    const float* ys = base + OFF_YS;
    const float* partials = base + OFF_PART;
    const int dir = dir0 + blockIdx.z;
    const int tid = threadIdx.x;
    __shared__ float red[8][33];
    __shared__ float cf[18];
    {
        int c = tid & 31, ks = tid >> 5;
        float a = 0.f;
        for (int k = ks * 128; k < ks * 128 + 128; k++) a += partials[k * 32 + c];
        red[ks][c] = a;
    }
    __syncthreads();
    if (tid < 32) {
        float a = 0.f;
        #pragma unroll
        for (int s2 = 1; s2 < 8; s2++) a += red[s2][tid];
        red[0][tid] += a;
    }
    __syncthreads();
    if (tid == 0) {
        float off = lin_b[dir];
        for (int c = 0; c < 16; c++) {
            float mu = red[0][c] * (1.f / 65536.f);
            float var = red[0][16 + c] * (1.f / 65536.f) - mu * mu;
            float inv = rsqrtf(var + 1e-5f);
            float coef = inv * gamma[dir * 16 + c] * lin_w[dir * 16 + c];
            cf[c] = coef;
            off += beta[dir * 16 + c] * lin_w[dir * 16 + c] - mu * coef;
        }
        cf[16] = off;
    }
    __syncthreads();

    const int b = blockIdx.x >> 3;
    const int jg = blockIdx.x & 7;
    const int j = jg * 32 + (tid >> 3);
    const int sub = tid & 7;
    float m = -3.4e38f;
    #pragma unroll
    for (int r = 0; r < 4; r++) {
        int l = j * PW + 8 * r + sub;
        const float* rowp = ys + (size_t)(b * 8192 + l) * 16;
        float sv = cf[16];
        #pragma unroll
        for (int k = 0; k < 4; k++) {
            float4 v4 = *(const float4*)(rowp + 4 * k);
            sv += fmaxf(v4.x, 0.f) * cf[4 * k] + fmaxf(v4.y, 0.f) * cf[4 * k + 1]
                + fmaxf(v4.z, 0.f) * cf[4 * k + 2] + fmaxf(v4.w, 0.f) * cf[4 * k + 3];
        }
        m = fmaxf(m, sv);
    }
    m = fmaxf(m, __shfl_xor(m, 1));
    m = fmaxf(m, __shfl_xor(m, 2));
    m = fmaxf(m, __shfl_xor(m, 4));
    if (sub == 0) out[b * 768 + dir * 256 + j] = m;
}

// ---------------------------------------------------------------------------
extern "C" void kernel_launch(void* const* d_in, const int* in_sizes, int n_in,
                              void* d_out, int out_size, void* d_ws, size_t ws_size,
                              hipStream_t stream) {
    const float* x     = (const float*)d_in[0];
    const float* Win   = (const float*)d_in[1];
    const float* convw = (const float*)d_in[2];
    const float* convb = (const float*)d_in[3];
    const float* dtb   = (const float*)d_in[4];
    const float* Alog  = (const float*)d_in[5];
    const float* Dp    = (const float*)d_in[6];
    const float* normw = (const float*)d_in[7];
    const float* Wout  = (const float*)d_in[8];
    const float* gamma = (const float*)d_in[9];
    const float* beta  = (const float*)d_in[10];
    const float* linw  = (const float*)d_in[11];
    const float* linb  = (const float*)d_in[12];
    float* out = (float*)d_out;
    float* ws = (float*)d_ws;

    const bool batched = ws_size >= (size_t)3 * PD * 4;
    const int nz = batched ? 3 : 1;
    const int dslm = batched ? 1 : 0;
    const int nloop = batched ? 1 : 3;

    for (int d0 = 0; d0 < nloop; ++d0) {
        k_delta<<<dim3(128, 8, nz), dim3(512), 0, stream>>>(
            x, Win, convw, convb, dtb, Alog, ws, d0, dslm);
        k_chunk_scan<<<dim3(512, 1, nz), dim3(64), 0, stream>>>(ws, dslm);
        k_out_epi<<<dim3(128, 8, nz), dim3(256), 0, stream>>>(
            x, Win, convw, convb, dtb, Alog, Dp, normw, Wout, ws, d0, dslm);
        k_pool_bn<<<dim3(64, 1, nz), dim3(256), 0, stream>>>(
            gamma, beta, linw, linb, ws, out, d0, dslm);
    }
}

// Round 6
// 380.765 us; speedup vs baseline: 2.8912x; 1.1500x over previous
//
#include <hip/hip_runtime.h>
#include <math.h>

#define CONVD 192
#define NC 128
#define PW 32
#define LOG2E 1.4426950408889634f
#define LN2f  0.69314718055994531f

// per-dir workspace offsets (floats)
#define OFF_DST   0u          // Dst  [8*16][128][256]  (delta -> Sin after scan)
#define OFF_CHA   4194304u    // chA  [8*16][128]
#define OFF_YS    4210688u    // ys   [8][8192][16]
#define OFF_PART  5259264u    // partials [1024][32]
#define PD        5292032u    // floats per dir region (21.2 MB)

// XOR-quad swizzle for [64][64] LDS tiles, element (row m, col t)
#define XSW(m, t)   ((m) * 64 + (((((t) >> 2) ^ ((m) & 15)) & 15) << 2) + ((t) & 3))
#define XSW4(m, tq) ((m) * 64 + ((((tq) ^ ((m) & 15)) & 15) << 2))

__device__ __forceinline__ float fast_silu(float x) {
    float e = __builtin_amdgcn_exp2f(-x * LOG2E);
    return x * __builtin_amdgcn_rcpf(1.f + e);
}
__device__ __forceinline__ float fast_softplus(float x) {
    if (x > 20.f) return x;
    float e = __builtin_amdgcn_exp2f(x * LOG2E);
    return LN2f * __builtin_amdgcn_logf(1.f + e);
}

template<int CTRL>
__device__ __forceinline__ float dpp_ror_add(float x) {
    int yi = __builtin_amdgcn_update_dpp(0, __float_as_int(x), CTRL, 0xf, 0xf, false);
    return x + __int_as_float(yi);
}
__device__ __forceinline__ float rowsum16(float x) {
    x = dpp_ror_add<0x128>(x);
    x = dpp_ror_add<0x124>(x);
    x = dpp_ror_add<0x122>(x);
    x = dpp_ror_add<0x121>(x);
    return x;
}

// stage u rows [pos][c] (67 x 16, pad 17) with 3-halo, zeros for l<0
template<int NT>
__device__ __forceinline__ void stage_u(
    const float* __restrict__ x, float* u_s, int b, int l0, int dir, int tid)
{
    for (int i = tid; i < 67 * 16; i += NT) {
        int pos = i >> 4, c = i & 15;
        int l = l0 + pos - 3;
        float v = 0.f;
        if (l >= 0) {
            if (dir == 0) {
                v = x[(b * 16 + c) * 8192 + l];
            } else if (dir == 1) {
                int h = l >> 9, w = (l >> 5) & 15, d = l & 31;
                v = x[(((b * 16 + c) * 32 + d) * 16 + h) * 16 + w];
            } else {
                int w = l >> 9, d = (l >> 4) & 31, h = l & 15;
                v = x[(((b * 16 + c) * 32 + d) * 16 + h) * 16 + w];
            }
        }
        u_s[pos * 17 + c] = v;
    }
}

// ---------------------------------------------------------------------------
// K_DELTA: proj (xh, B, dt only) + conv + silu + scan + chunk state delta.
// Writes ONLY Dst + chA. grid (128 ck, 8 b, nz), 512 threads.
// ---------------------------------------------------------------------------
__global__ __launch_bounds__(512, 6) void k_delta(
    const float* __restrict__ x, const float* __restrict__ Win,
    const float* __restrict__ convw, const float* __restrict__ convb,
    const float* __restrict__ dtb, const float* __restrict__ A_log,
    float* __restrict__ ws, int dir0, int dslm)
{
    __shared__ float u_s[67 * 17];
    __shared__ float xh_c[4096];   // [d][t] swizzled; becomes wx
    __shared__ float Bs[4096];     // [n][t] swizzled
    __shared__ float dts[16 * 65];
    __shared__ float wbuf[16 * 65];
    const int tid = threadIdx.x;
    const int ck = blockIdx.x;
    const int b = blockIdx.y;
    const int dir = dir0 + blockIdx.z;
    float* base = ws + (size_t)(dslm * blockIdx.z) * PD;
    float* Dst = base + OFF_DST;
    float* chA = base + OFF_CHA;
    const int l0 = ck * 64;

    stage_u<512>(x, u_s, b, l0, dir, tid);
    __syncthreads();

    const int lane = tid & 63;
    const int wv = __builtin_amdgcn_readfirstlane(tid >> 6);

    float u[16], uh[16];
    {
        const float* ur = &u_s[(lane + 3) * 17];
        #pragma unroll
        for (int k = 0; k < 16; k++) u[k] = ur[k];
        const float* uhr = &u_s[(lane < 3 ? lane : 0) * 17];
        #pragma unroll
        for (int k = 0; k < 16; k++) uh[k] = uhr[k];
    }

    // 144 cols (xh 64..127, B 128..191, dt 256..271) over 8 waves
    for (int i = 0; i < 18; i++) {
        const int g = wv * 18 + i;
        const int col = (g < 128) ? (64 + g) : (256 + (g - 128));
        const float* wp = Win + (size_t)(dir * 272 + col) * 16;
        float acc = 0.f, hacc = 0.f;
        #pragma unroll
        for (int k = 0; k < 16; k++) {
            acc += u[k] * wp[k];
            hacc += uh[k] * wp[k];
        }
        if (col < 256) {
            const int ch = col - 64;
            float v1 = __shfl_up(acc, 1);
            float v2 = __shfl_up(acc, 2);
            float v3 = __shfl_up(acc, 3);
            float h0 = __shfl(hacc, 0);
            float h1 = __shfl(hacc, 1);
            float h2 = __shfl(hacc, 2);
            float m1 = (lane >= 1) ? v1 : h2;
            float m2 = (lane >= 2) ? v2 : ((lane == 0) ? h1 : h2);
            float m3 = (lane >= 3) ? v3 : ((lane == 0) ? h0 : ((lane == 1) ? h1 : h2));
            const float* cwp = convw + (size_t)(dir * CONVD + ch) * 4;
            float conv = convb[dir * CONVD + ch]
                       + cwp[0] * m3 + cwp[1] * m2 + cwp[2] * m1 + cwp[3] * acc;
            float xv = fast_silu(conv);
            if (ch < 64) xh_c[XSW(ch, lane)] = xv;
            else         Bs[XSW(ch - 64, lane)] = xv;
        } else {
            const int h = col - 256;
            dts[h * 65 + lane] = fast_softplus(acc + dtb[dir * 16 + h]);
        }
    }
    __syncthreads();

    // per-head cumulative log2-decay scan (2 heads per wave)
    for (int h = wv; h < 16; h += 8) {
        float A2 = -expf(A_log[dir * 16 + h]) * LOG2E;
        float dtv = dts[h * 65 + lane];
        float v = dtv * A2;
        #pragma unroll
        for (int off = 1; off < 64; off <<= 1) {
            float o = __shfl_up(v, off, 64);
            if (lane >= off) v += o;
        }
        float tot = __shfl(v, 63, 64);
        wbuf[h * 65 + lane] = __builtin_amdgcn_exp2f(tot - v) * dtv;
        if (lane == 63) chA[(b * 16 + h) * 128 + ck] = __builtin_amdgcn_exp2f(tot);
    }
    __syncthreads();

    // wx[d][t] = wbuf[h][t] * xh[d][t]
    for (int j = tid; j < 4096; j += 512) {
        int hp = j >> 6, t = j & 63;
        xh_c[XSW(hp, t)] *= wbuf[(hp >> 2) * 65 + t];
    }
    __syncthreads();

    // Dst[hp][n] = sum_t wx[hp][t] * B[n][t]
    if (tid < 256) {
        const int hp4 = tid >> 4, n4 = tid & 15;
        float a[4][4] = {};
        for (int tq = 0; tq < 16; tq++) {
            float4 xv[4], bv[4];
            #pragma unroll
            for (int i2 = 0; i2 < 4; i2++) {
                xv[i2] = *(const float4*)&xh_c[XSW4(4 * hp4 + i2, tq)];
                bv[i2] = *(const float4*)&Bs[XSW4(4 * n4 + i2, tq)];
            }
            #pragma unroll
            for (int i2 = 0; i2 < 4; i2++)
                #pragma unroll
                for (int j2 = 0; j2 < 4; j2++)
                    a[i2][j2] += xv[i2].x * bv[j2].x + xv[i2].y * bv[j2].y
                               + xv[i2].z * bv[j2].z + xv[i2].w * bv[j2].w;
        }
        #pragma unroll
        for (int i2 = 0; i2 < 4; i2++) {
            int hp = 4 * hp4 + i2;
            int h = hp >> 2, p = hp & 3;
            *(float4*)(Dst + ((size_t)((b * 16 + h) * 128 + ck)) * 256 + p * 64 + 4 * n4) =
                make_float4(a[i2][0], a[i2][1], a[i2][2], a[i2][3]);
        }
    }
}

// ---------------------------------------------------------------------------
// K_SCAN: inter-chunk scan, in place. grid (512, 1, nz) x 64 threads.
// ---------------------------------------------------------------------------
__global__ __launch_bounds__(64) void k_chunk_scan(
    float* __restrict__ ws, int dslm)
{
    float* base = ws + (size_t)(dslm * blockIdx.z) * PD;
    float* Dst = base + OFF_DST;
    const float* chA = base + OFF_CHA;
    const int bh = blockIdx.x >> 2;
    const int elem = (blockIdx.x & 3) * 64 + threadIdx.x;
    float S = 0.f;
    for (int k0 = 0; k0 < NC; k0 += 8) {
        float d[8], av[8];
        #pragma unroll
        for (int j = 0; j < 8; j++) {
            d[j] = Dst[((size_t)(bh * 128 + k0 + j)) * 256 + elem];
            av[j] = chA[bh * 128 + k0 + j];
        }
        #pragma unroll
        for (int j = 0; j < 8; j++) {
            Dst[((size_t)(bh * 128 + k0 + j)) * 256 + elem] = S;
            S = av[j] * S + d[j];
        }
    }
}

// ---------------------------------------------------------------------------
// K_OUT_EPI: full recompute of front from x, then chunk output + epilogue +
// BN partials. grid (128 ck, 8 b, nz), 512 threads:
// heads split across two 256-thread groups in phase F (yv LDS exchange).
// ---------------------------------------------------------------------------
__global__ __launch_bounds__(512, 4) void k_out_epi(
    const float* __restrict__ x, const float* __restrict__ Win,
    const float* __restrict__ convw, const float* __restrict__ convb,
    const float* __restrict__ dtb, const float* __restrict__ A_log,
    const float* __restrict__ Dp, const float* __restrict__ normw,
    const float* __restrict__ Wout, float* __restrict__ ws, int dir0, int dslm)
{
    __shared__ float SinT[64 * 65];   // [n][hp] pad 65 (2-way banks both sides)
    __shared__ float xh_c[4096];      // [d][t] swizzled
    __shared__ float Bz[4096];        // B [n][t] swz, then z [d][t] swz
    __shared__ float Cy[4352];        // C [n][t] swz (4096), then yv[64][4][17]
    __shared__ float uW[67 * 17];     // u_s, then WoN [16][65]
    __shared__ float dts[16 * 65];
    __shared__ float ct2l[16 * 65];
    __shared__ float Dps[16];
    __shared__ float red[4][34];
    float* base = ws + (size_t)(dslm * blockIdx.z) * PD;
    const float* Dst = base + OFF_DST;
    float* ys        = base + OFF_YS;
    float* partials  = base + OFF_PART;
    const int dir = dir0 + blockIdx.z;
    const int tid = threadIdx.x;
    const int b = blockIdx.y;
    const int ck = blockIdx.x;
    const int l0 = ck * 64;
    const int tg = tid & 255;
    const int t4 = tg >> 4, x4 = tg & 15;
    const int grp = tid >> 8;
    const int lane = tid & 63;
    const int wv = __builtin_amdgcn_readfirstlane(tid >> 6);

    // phase A: stage u + SinT + Dps
    stage_u<512>(x, uW, b, l0, dir, tid);
    for (int j = tid; j < 1024; j += 512) {
        int hp = j >> 4, n4 = (j & 15) << 2;
        int h = hp >> 2, p = hp & 3;
        float4 sv = *(const float4*)(Dst + ((size_t)((b * 16 + h) * 128 + ck)) * 256 + p * 64 + n4);
        SinT[(n4 + 0) * 65 + hp] = sv.x;
        SinT[(n4 + 1) * 65 + hp] = sv.y;
        SinT[(n4 + 2) * 65 + hp] = sv.z;
        SinT[(n4 + 3) * 65 + hp] = sv.w;
    }
    if (tid < 16) Dps[tid] = Dp[dir * 16 + tid];
    __syncthreads();

    float u[16], uh[16];
    {
        const float* ur = &uW[(lane + 3) * 17];
        #pragma unroll
        for (int k = 0; k < 16; k++) u[k] = ur[k];
        const float* uhr = &uW[(lane < 3 ? lane : 0) * 17];
        #pragma unroll
        for (int k = 0; k < 16; k++) uh[k] = uhr[k];
    }

    // phase B: proj cols 64..271 (xh, B, C, dt); 8 waves x 26 cols
    for (int i = 0; i < 26; i++) {
        const int col = 64 + wv * 26 + i;
        const float* wp = Win + (size_t)(dir * 272 + col) * 16;
        float acc = 0.f, hacc = 0.f;
        #pragma unroll
        for (int k = 0; k < 16; k++) {
            acc += u[k] * wp[k];
            hacc += uh[k] * wp[k];
        }
        if (col < 256) {
            const int ch = col - 64;
            float v1 = __shfl_up(acc, 1);
            float v2 = __shfl_up(acc, 2);
            float v3 = __shfl_up(acc, 3);
            float h0 = __shfl(hacc, 0);
            float h1 = __shfl(hacc, 1);
            float h2 = __shfl(hacc, 2);
            float m1 = (lane >= 1) ? v1 : h2;
            float m2 = (lane >= 2) ? v2 : ((lane == 0) ? h1 : h2);
            float m3 = (lane >= 3) ? v3 : ((lane == 0) ? h0 : ((lane == 1) ? h1 : h2));
            const float* cwp = convw + (size_t)(dir * CONVD + ch) * 4;
            float conv = convb[dir * CONVD + ch]
                       + cwp[0] * m3 + cwp[1] * m2 + cwp[2] * m1 + cwp[3] * acc;
            float xv = fast_silu(conv);
            if (ch < 64)       xh_c[XSW(ch, lane)] = xv;
            else if (ch < 128) Bz[XSW(ch - 64, lane)] = xv;
            else               Cy[XSW(ch - 128, lane)] = xv;
        } else {
            const int h = col - 256;
            dts[h * 65 + lane] = fast_softplus(acc + dtb[dir * 16 + h]);
        }
    }
    __syncthreads();

    // phase C: scan -> ct2 (LDS only); 8 waves x 2 heads
    for (int h = wv; h < 16; h += 8) {
        float A2 = -expf(A_log[dir * 16 + h]) * LOG2E;
        float dtv = dts[h * 65 + lane];
        float v = dtv * A2;
        #pragma unroll
        for (int off = 1; off < 64; off <<= 1) {
            float o = __shfl_up(v, off, 64);
            if (lane >= off) v += o;
        }
        ct2l[h * 65 + lane] = v;
    }
    __syncthreads();

    // phase D (per 256-group, redundant): G[t][s], CS[t][hp]
    float G_[4][4] = {}, CS_[4][4] = {};
    for (int n = 0; n < 64; n++) {
        float4 cr4 = *(const float4*)&Cy[XSW4(n, t4)];
        float4 br4 = *(const float4*)&Bz[XSW4(n, x4)];
        float cr[4] = {cr4.x, cr4.y, cr4.z, cr4.w};
        float br[4] = {br4.x, br4.y, br4.z, br4.w};
        float sn[4];
        #pragma unroll
        for (int q = 0; q < 4; q++) sn[q] = SinT[n * 65 + 4 * x4 + q];
        #pragma unroll
        for (int r = 0; r < 4; r++)
            #pragma unroll
            for (int q = 0; q < 4; q++) {
                G_[r][q] += cr[r] * br[q];
                CS_[r][q] += cr[r] * sn[q];
            }
    }
    __syncthreads();  // B, C, SinT dead

    // phase E: proj z (cols 0..63) into Bz; WoN into uW
    for (int i = 0; i < 8; i++) {
        const int col = wv * 8 + i;
        const float* wp = Win + (size_t)(dir * 272 + col) * 16;
        float acc = 0.f;
        #pragma unroll
        for (int k = 0; k < 16; k++) acc += u[k] * wp[k];
        Bz[XSW(col, lane)] = acc;
    }
    __syncthreads();
    for (int j = tid; j < 1024; j += 512) {
        int c = j >> 6, d = j & 63;
        uW[c * 65 + d] = Wout[dir * 1024 + j] * normw[dir * 64 + d];
    }
    __syncthreads();

    // phase F: per-head y; group g handles heads 8g..8g+7; results -> yv LDS
    float* yv = Cy;  // [64 rows][4 p][17]
    const int tbase = 4 * t4;
    #pragma unroll 1
    for (int hh = 0; hh < 8; hh++) {
        const int h = 8 * grp + hh;
        float ctt[4], ect[4];
        #pragma unroll
        for (int r = 0; r < 4; r++) {
            ctt[r] = ct2l[h * 65 + tbase + r];
            ect[r] = __builtin_amdgcn_exp2f(ctt[r]);
        }
        float acc[4][4] = {};  // [r][p]
        #pragma unroll
        for (int q = 0; q < 4; q++) {
            int s = 4 * x4 + q;
            float cs_ = ct2l[h * 65 + s];
            float dtq = dts[h * 65 + s];
            float xv[4];
            #pragma unroll
            for (int p = 0; p < 4; p++) {
                int m = 4 * h + p;
                xv[p] = xh_c[m * 64 + (((x4 ^ (m & 15)) & 15) << 2) + q];
            }
            #pragma unroll
            for (int r = 0; r < 4; r++) {
                float e = __builtin_amdgcn_exp2f(ctt[r] - cs_);
                e = (s <= tbase + r) ? e : 0.f;
                float w = G_[r][q] * e * dtq;
                #pragma unroll
                for (int p = 0; p < 4; p++) acc[r][p] += w * xv[p];
            }
        }
        if (x4 == h) {
            #pragma unroll
            for (int r = 0; r < 4; r++)
                #pragma unroll
                for (int p = 0; p < 4; p++)
                    acc[r][p] += ect[r] * CS_[r][p];
        }
        #pragma unroll
        for (int r = 0; r < 4; r++)
            #pragma unroll
            for (int p = 0; p < 4; p++)
                acc[r][p] = rowsum16(acc[r][p]);
        float outv = acc[0][0];
        #pragma unroll
        for (int r = 0; r < 4; r++)
            #pragma unroll
            for (int p = 0; p < 4; p++)
                if (r || p) outv = (x4 == r * 4 + p) ? acc[r][p] : outv;
        const int row = tbase + (x4 >> 2);
        const int pp = x4 & 3;
        yv[(row * 4 + pp) * 17 + h] = outv;
    }
    __syncthreads();

    // phase G: epilogue on tid<256: lane = (row = tid>>2, p = tid&3)
    float os[4];
    const int row = tid >> 2;
    const int p = tid & 3;
    if (tid < 256) {
        float gg[16], sumsq = 0.f;
        #pragma unroll
        for (int h = 0; h < 16; h++) {
            float yval = yv[(row * 4 + p) * 17 + h];
            int m = 4 * h + p;
            int ax = m * 64 + ((((row >> 2) ^ (m & 15)) & 15) << 2) + (row & 3);
            float xh = xh_c[ax];
            float zv = Bz[ax];
            float val = (yval + Dps[h] * xh) * fast_silu(zv);
            gg[h] = val;
            sumsq += val * val;
        }
        sumsq += __shfl_xor(sumsq, 1);
        sumsq += __shfl_xor(sumsq, 2);
        float rms = rsqrtf(sumsq * (1.f / 64.f) + 1e-5f);

        float oc[16];
        #pragma unroll
        for (int c = 0; c < 16; c++) {
            float a = 0.f;
            #pragma unroll
            for (int h = 0; h < 16; h++) a += gg[h] * uW[c * 65 + 4 * h + p];
            oc[c] = a;
        }
        #pragma unroll
        for (int c = 0; c < 16; c++) {
            oc[c] += __shfl_xor(oc[c], 1);
            oc[c] += __shfl_xor(oc[c], 2);
        }
        #pragma unroll
        for (int i2 = 0; i2 < 4; i2++) {
            float a0 = (p == 0) ? oc[i2] : oc[4 + i2];
            float a1 = (p == 2) ? oc[8 + i2] : oc[12 + i2];
            os[i2] = (((p & 2) == 0) ? a0 : a1) * rms;
        }
        size_t bl = (size_t)(b * 8192 + l0 + row);
        *(float4*)(ys + bl * 16 + 4 * p) = make_float4(os[0], os[1], os[2], os[3]);

        // BN partials (4 waves of readers)
        float bs[4], bq[4];
        #pragma unroll
        for (int i2 = 0; i2 < 4; i2++) {
            float vv = fmaxf(os[i2], 0.f);
            bs[i2] = vv;
            bq[i2] = vv * vv;
        }
        #pragma unroll
        for (int off = 4; off < 64; off <<= 1) {
            #pragma unroll
            for (int i2 = 0; i2 < 4; i2++) {
                bs[i2] += __shfl_xor(bs[i2], off);
                bq[i2] += __shfl_xor(bq[i2], off);
            }
        }
        const int wlane = tid & 63, wvid = tid >> 6;
        if (wlane < 4) {
            #pragma unroll
            for (int i2 = 0; i2 < 4; i2++) {
                red[wvid][4 * wlane + i2] = bs[i2];
                red[wvid][16 + 4 * wlane + i2] = bq[i2];
            }
        }
    }
    __syncthreads();
    if (tid < 32) {
        float a = red[0][tid] + red[1][tid] + red[2][tid] + red[3][tid];
        partials[((size_t)(b * 128 + ck)) * 32 + tid] = a;
    }
}

// ---------------------------------------------------------------------------
// K_POOL_BN: reduce partials -> BN coefs, then BN + linear + maxpool(32).
// ---------------------------------------------------------------------------
__global__ __launch_bounds__(256) void k_pool_bn(
    const float* __restrict__ gamma, const float* __restrict__ beta,
    const float* __restrict__ lin_w, const float* __restrict__ lin_b,
    float* __restrict__ ws, float* __restrict__ out, int dir0, int dslm)
{
    float* base = ws + (size_t)(dslm * blockIdx.z) * PD;
    const float* ys = base + OFF_YS;
    const float* partials = base + OFF_PART;
    const int dir = dir0 + blockIdx.z;
    const int tid = threadIdx.x;
    __shared__ float red[8][33];
    __shared__ float cf[18];
    {
        int c = tid & 31, ks = tid >> 5;
        float a = 0.f;
        for (int k = ks * 128; k < ks * 128 + 128; k++) a += partials[k * 32 + c];
        red[ks][c] = a;
    }
    __syncthreads();
    if (tid < 32) {
        float a = 0.f;
        #pragma unroll
        for (int s2 = 1; s2 < 8; s2++) a += red[s2][tid];
        red[0][tid] += a;
    }
    __syncthreads();
    if (tid == 0) {
        float off = lin_b[dir];
        for (int c = 0; c < 16; c++) {
            float mu = red[0][c] * (1.f / 65536.f);
            float var = red[0][16 + c] * (1.f / 65536.f) - mu * mu;
            float inv = rsqrtf(var + 1e-5f);
            float coef = inv * gamma[dir * 16 + c] * lin_w[dir * 16 + c];
            cf[c] = coef;
            off += beta[dir * 16 + c] * lin_w[dir * 16 + c] - mu * coef;
        }
        cf[16] = off;
    }
    __syncthreads();

    const int b = blockIdx.x >> 3;
    const int jg = blockIdx.x & 7;
    const int j = jg * 32 + (tid >> 3);
    const int sub = tid & 7;
    float m = -3.4e38f;
    #pragma unroll
    for (int r = 0; r < 4; r++) {
        int l = j * PW + 8 * r + sub;
        const float* rowp = ys + (size_t)(b * 8192 + l) * 16;
        float sv = cf[16];
        #pragma unroll
        for (int k = 0; k < 4; k++) {
            float4 v4 = *(const float4*)(rowp + 4 * k);
            sv += fmaxf(v4.x, 0.f) * cf[4 * k] + fmaxf(v4.y, 0.f) * cf[4 * k + 1]
                + fmaxf(v4.z, 0.f) * cf[4 * k + 2] + fmaxf(v4.w, 0.f) * cf[4 * k + 3];
        }
        m = fmaxf(m, sv);
    }
    m = fmaxf(m, __shfl_xor(m, 1));
    m = fmaxf(m, __shfl_xor(m, 2));
    m = fmaxf(m, __shfl_xor(m, 4));
    if (sub == 0) out[b * 768 + dir * 256 + j] = m;
}

// ---------------------------------------------------------------------------
extern "C" void kernel_launch(void* const* d_in, const int* in_sizes, int n_in,
                              void* d_out, int out_size, void* d_ws, size_t ws_size,
                              hipStream_t stream) {
    const float* x     = (const float*)d_in[0];
    const float* Win   = (const float*)d_in[1];
    const float* convw = (const float*)d_in[2];
    const float* convb = (const float*)d_in[3];
    const float* dtb   = (const float*)d_in[4];
    const float* Alog  = (const float*)d_in[5];
    const float* Dp    = (const float*)d_in[6];
    const float* normw = (const float*)d_in[7];
    const float* Wout  = (const float*)d_in[8];
    const float* gamma = (const float*)d_in[9];
    const float* beta  = (const float*)d_in[10];
    const float* linw  = (const float*)d_in[11];
    const float* linb  = (const float*)d_in[12];
    float* out = (float*)d_out;
    float* ws = (float*)d_ws;

    const bool batched = ws_size >= (size_t)3 * PD * 4;
    const int nz = batched ? 3 : 1;
    const int dslm = batched ? 1 : 0;
    const int nloop = batched ? 1 : 3;

    for (int d0 = 0; d0 < nloop; ++d0) {
        k_delta<<<dim3(128, 8, nz), dim3(512), 0, stream>>>(
            x, Win, convw, convb, dtb, Alog, ws, d0, dslm);
        k_chunk_scan<<<dim3(512, 1, nz), dim3(64), 0, stream>>>(ws, dslm);
        k_out_epi<<<dim3(128, 8, nz), dim3(512), 0, stream>>>(
            x, Win, convw, convb, dtb, Alog, Dp, normw, Wout, ws, d0, dslm);
        k_pool_bn<<<dim3(64, 1, nz), dim3(256), 0, stream>>>(
            gamma, beta, linw, linb, ws, out, d0, dslm);
    }
}

// Round 8
// 356.089 us; speedup vs baseline: 3.0915x; 1.0693x over previous
//
#include <hip/hip_runtime.h>
#include <math.h>

#define CONVD 192
#define NC 128
#define PW 32
#define LOG2E 1.4426950408889634f
#define LN2f  0.69314718055994531f

// per-dir workspace offsets (floats)
#define OFF_DST   0u          // Dst  [8*16][128][256]  (delta -> Sin after scan)
#define OFF_CHA   4194304u    // chA  [8*16][128]
#define OFF_YS    4210688u    // ys   [8][8192][16]
#define OFF_PART  5259264u    // partials [1024][32]
#define PD        5292032u    // floats per dir region (21.2 MB)

// XOR-quad swizzle for [64][64] LDS tiles, element (row m, col t)
#define XSW(m, t)   ((m) * 64 + (((((t) >> 2) ^ ((m) & 15)) & 15) << 2) + ((t) & 3))
#define XSW4(m, tq) ((m) * 64 + ((((tq) ^ ((m) & 15)) & 15) << 2))

__device__ __forceinline__ float fast_silu(float x) {
    float e = __builtin_amdgcn_exp2f(-x * LOG2E);
    return x * __builtin_amdgcn_rcpf(1.f + e);
}
__device__ __forceinline__ float fast_softplus(float x) {
    if (x > 20.f) return x;
    float e = __builtin_amdgcn_exp2f(x * LOG2E);
    return LN2f * __builtin_amdgcn_logf(1.f + e);
}

// stage u rows [pos][c] (67 x 16, pad 17) with 3-halo, zeros for l<0
template<int NT>
__device__ __forceinline__ void stage_u(
    const float* __restrict__ x, float* u_s, int b, int l0, int dir, int tid)
{
    for (int i = tid; i < 67 * 16; i += NT) {
        int pos = i >> 4, c = i & 15;
        int l = l0 + pos - 3;
        float v = 0.f;
        if (l >= 0) {
            if (dir == 0) {
                v = x[(b * 16 + c) * 8192 + l];
            } else if (dir == 1) {
                int h = l >> 9, w = (l >> 5) & 15, d = l & 31;
                v = x[(((b * 16 + c) * 32 + d) * 16 + h) * 16 + w];
            } else {
                int w = l >> 9, d = (l >> 4) & 31, h = l & 15;
                v = x[(((b * 16 + c) * 32 + d) * 16 + h) * 16 + w];
            }
        }
        u_s[pos * 17 + c] = v;
    }
}

// ---------------------------------------------------------------------------
// K_DELTA: proj (xh, B, dt only) + conv + silu + scan + chunk state delta.
// ---------------------------------------------------------------------------
__global__ __launch_bounds__(512, 6) void k_delta(
    const float* __restrict__ x, const float* __restrict__ Win,
    const float* __restrict__ convw, const float* __restrict__ convb,
    const float* __restrict__ dtb, const float* __restrict__ A_log,
    float* __restrict__ ws, int dir0, int dslm)
{
    __shared__ float u_s[67 * 17];
    __shared__ float xh_c[4096];
    __shared__ float Bs[4096];
    __shared__ float dts[16 * 65];
    __shared__ float wbuf[16 * 65];
    const int tid = threadIdx.x;
    const int ck = blockIdx.x;
    const int b = blockIdx.y;
    const int dir = dir0 + blockIdx.z;
    float* base = ws + (size_t)(dslm * blockIdx.z) * PD;
    float* Dst = base + OFF_DST;
    float* chA = base + OFF_CHA;
    const int l0 = ck * 64;

    stage_u<512>(x, u_s, b, l0, dir, tid);
    __syncthreads();

    const int lane = tid & 63;
    const int wv = __builtin_amdgcn_readfirstlane(tid >> 6);

    float u[16], uh[16];
    {
        const float* ur = &u_s[(lane + 3) * 17];
        #pragma unroll
        for (int k = 0; k < 16; k++) u[k] = ur[k];
        const float* uhr = &u_s[(lane < 3 ? lane : 0) * 17];
        #pragma unroll
        for (int k = 0; k < 16; k++) uh[k] = uhr[k];
    }

    for (int i = 0; i < 18; i++) {
        const int g = wv * 18 + i;
        const int col = (g < 128) ? (64 + g) : (256 + (g - 128));
        const float* wp = Win + (size_t)(dir * 272 + col) * 16;
        float acc = 0.f, hacc = 0.f;
        #pragma unroll
        for (int k = 0; k < 16; k++) {
            acc += u[k] * wp[k];
            hacc += uh[k] * wp[k];
        }
        if (col < 256) {
            const int ch = col - 64;
            float v1 = __shfl_up(acc, 1);
            float v2 = __shfl_up(acc, 2);
            float v3 = __shfl_up(acc, 3);
            float h0 = __shfl(hacc, 0);
            float h1 = __shfl(hacc, 1);
            float h2 = __shfl(hacc, 2);
            float m1 = (lane >= 1) ? v1 : h2;
            float m2 = (lane >= 2) ? v2 : ((lane == 0) ? h1 : h2);
            float m3 = (lane >= 3) ? v3 : ((lane == 0) ? h0 : ((lane == 1) ? h1 : h2));
            const float* cwp = convw + (size_t)(dir * CONVD + ch) * 4;
            float conv = convb[dir * CONVD + ch]
                       + cwp[0] * m3 + cwp[1] * m2 + cwp[2] * m1 + cwp[3] * acc;
            float xv = fast_silu(conv);
            if (ch < 64) xh_c[XSW(ch, lane)] = xv;
            else         Bs[XSW(ch - 64, lane)] = xv;
        } else {
            const int h = col - 256;
            dts[h * 65 + lane] = fast_softplus(acc + dtb[dir * 16 + h]);
        }
    }
    __syncthreads();

    for (int h = wv; h < 16; h += 8) {
        float A2 = -expf(A_log[dir * 16 + h]) * LOG2E;
        float dtv = dts[h * 65 + lane];
        float v = dtv * A2;
        #pragma unroll
        for (int off = 1; off < 64; off <<= 1) {
            float o = __shfl_up(v, off, 64);
            if (lane >= off) v += o;
        }
        float tot = __shfl(v, 63, 64);
        wbuf[h * 65 + lane] = __builtin_amdgcn_exp2f(tot - v) * dtv;
        if (lane == 63) chA[(b * 16 + h) * 128 + ck] = __builtin_amdgcn_exp2f(tot);
    }
    __syncthreads();

    for (int j = tid; j < 4096; j += 512) {
        int hp = j >> 6, t = j & 63;
        xh_c[XSW(hp, t)] *= wbuf[(hp >> 2) * 65 + t];
    }
    __syncthreads();

    if (tid < 256) {
        const int hp4 = tid >> 4, n4 = tid & 15;
        float a[4][4] = {};
        for (int tq = 0; tq < 16; tq++) {
            float4 xv[4], bv[4];
            #pragma unroll
            for (int i2 = 0; i2 < 4; i2++) {
                xv[i2] = *(const float4*)&xh_c[XSW4(4 * hp4 + i2, tq)];
                bv[i2] = *(const float4*)&Bs[XSW4(4 * n4 + i2, tq)];
            }
            #pragma unroll
            for (int i2 = 0; i2 < 4; i2++)
                #pragma unroll
                for (int j2 = 0; j2 < 4; j2++)
                    a[i2][j2] += xv[i2].x * bv[j2].x + xv[i2].y * bv[j2].y
                               + xv[i2].z * bv[j2].z + xv[i2].w * bv[j2].w;
        }
        #pragma unroll
        for (int i2 = 0; i2 < 4; i2++) {
            int hp = 4 * hp4 + i2;
            int h = hp >> 2, p = hp & 3;
            *(float4*)(Dst + ((size_t)((b * 16 + h) * 128 + ck)) * 256 + p * 64 + 4 * n4) =
                make_float4(a[i2][0], a[i2][1], a[i2][2], a[i2][3]);
        }
    }
}

// ---------------------------------------------------------------------------
// K_SCAN: inter-chunk scan, in place.
// ---------------------------------------------------------------------------
__global__ __launch_bounds__(64) void k_chunk_scan(
    float* __restrict__ ws, int dslm)
{
    float* base = ws + (size_t)(dslm * blockIdx.z) * PD;
    float* Dst = base + OFF_DST;
    const float* chA = base + OFF_CHA;
    const int bh = blockIdx.x >> 2;
    const int elem = (blockIdx.x & 3) * 64 + threadIdx.x;
    float S = 0.f;
    for (int k0 = 0; k0 < NC; k0 += 8) {
        float d[8], av[8];
        #pragma unroll
        for (int j = 0; j < 8; j++) {
            d[j] = Dst[((size_t)(bh * 128 + k0 + j)) * 256 + elem];
            av[j] = chA[bh * 128 + k0 + j];
        }
        #pragma unroll
        for (int j = 0; j < 8; j++) {
            Dst[((size_t)(bh * 128 + k0 + j)) * 256 + elem] = S;
            S = av[j] * S + d[j];
        }
    }
}

// ---------------------------------------------------------------------------
// K_OUT_EPI: full recompute of front from x, then chunk output + epilogue +
// BN partials. grid (128 ck, 8 b, nz), 512 threads.
// Group 0 computes G (full n), group 1 computes CS (full n); LDS exchange.
// Phase F: DIRECT exp2 per (r,q) (safe: kept exponents <= 0; masked entries
// discard inf via select before any inf*0 product) + butterfly reduce-scatter.
// ---------------------------------------------------------------------------
__global__ __launch_bounds__(512, 4) void k_out_epi(
    const float* __restrict__ x, const float* __restrict__ Win,
    const float* __restrict__ convw, const float* __restrict__ convb,
    const float* __restrict__ dtb, const float* __restrict__ A_log,
    const float* __restrict__ Dp, const float* __restrict__ normw,
    const float* __restrict__ Wout, float* __restrict__ ws, int dir0, int dslm)
{
    __shared__ float SinT[64 * 65];   // [n][hp]; then CS exchange [16][129]
    __shared__ float xh_c[4096];      // [d][t] swizzled
    __shared__ float Bz[4096];        // B [n][t] swz, then z [d][t] swz
    __shared__ float Cy[4352];        // C [n][t] swz; then G exch [16][257]; then yv
    __shared__ float uW[67 * 17];     // u_s, then WoN [16][65]
    __shared__ float dts[16 * 68];
    __shared__ float ct2l[16 * 68];
    __shared__ float Dps[16];
    __shared__ float red[4][34];
    float* base = ws + (size_t)(dslm * blockIdx.z) * PD;
    const float* Dst = base + OFF_DST;
    float* ys        = base + OFF_YS;
    float* partials  = base + OFF_PART;
    const int dir = dir0 + blockIdx.z;
    const int tid = threadIdx.x;
    const int b = blockIdx.y;
    const int ck = blockIdx.x;
    const int l0 = ck * 64;
    const int tg = tid & 255;
    const int t4 = tg >> 4, x4 = tg & 15;
    const int grp = tid >> 8;
    const int lane = tid & 63;
    const int wv = __builtin_amdgcn_readfirstlane(tid >> 6);

    // phase A: stage u + SinT + Dps
    stage_u<512>(x, uW, b, l0, dir, tid);
    for (int j = tid; j < 1024; j += 512) {
        int hp = j >> 4, n4 = (j & 15) << 2;
        int h = hp >> 2, p = hp & 3;
        float4 sv = *(const float4*)(Dst + ((size_t)((b * 16 + h) * 128 + ck)) * 256 + p * 64 + n4);
        SinT[(n4 + 0) * 65 + hp] = sv.x;
        SinT[(n4 + 1) * 65 + hp] = sv.y;
        SinT[(n4 + 2) * 65 + hp] = sv.z;
        SinT[(n4 + 3) * 65 + hp] = sv.w;
    }
    if (tid < 16) Dps[tid] = Dp[dir * 16 + tid];
    __syncthreads();

    float u[16], uh[16];
    {
        const float* ur = &uW[(lane + 3) * 17];
        #pragma unroll
        for (int k = 0; k < 16; k++) u[k] = ur[k];
        const float* uhr = &uW[(lane < 3 ? lane : 0) * 17];
        #pragma unroll
        for (int k = 0; k < 16; k++) uh[k] = uhr[k];
    }

    // phase B: proj cols 64..271 (xh, B, C, dt); 8 waves x 26 cols
    for (int i = 0; i < 26; i++) {
        const int col = 64 + wv * 26 + i;
        const float* wp = Win + (size_t)(dir * 272 + col) * 16;
        float acc = 0.f, hacc = 0.f;
        #pragma unroll
        for (int k = 0; k < 16; k++) {
            acc += u[k] * wp[k];
            hacc += uh[k] * wp[k];
        }
        if (col < 256) {
            const int ch = col - 64;
            float v1 = __shfl_up(acc, 1);
            float v2 = __shfl_up(acc, 2);
            float v3 = __shfl_up(acc, 3);
            float h0 = __shfl(hacc, 0);
            float h1 = __shfl(hacc, 1);
            float h2 = __shfl(hacc, 2);
            float m1 = (lane >= 1) ? v1 : h2;
            float m2 = (lane >= 2) ? v2 : ((lane == 0) ? h1 : h2);
            float m3 = (lane >= 3) ? v3 : ((lane == 0) ? h0 : ((lane == 1) ? h1 : h2));
            const float* cwp = convw + (size_t)(dir * CONVD + ch) * 4;
            float conv = convb[dir * CONVD + ch]
                       + cwp[0] * m3 + cwp[1] * m2 + cwp[2] * m1 + cwp[3] * acc;
            float xv = fast_silu(conv);
            if (ch < 64)       xh_c[XSW(ch, lane)] = xv;
            else if (ch < 128) Bz[XSW(ch - 64, lane)] = xv;
            else               Cy[XSW(ch - 128, lane)] = xv;
        } else {
            const int h = col - 256;
            dts[h * 68 + lane] = fast_softplus(acc + dtb[dir * 16 + h]);
        }
    }
    __syncthreads();

    // phase C: scan -> ct2 (LDS only); 8 waves x 2 heads
    for (int h = wv; h < 16; h += 8) {
        float A2 = -expf(A_log[dir * 16 + h]) * LOG2E;
        float dtv = dts[h * 68 + lane];
        float v = dtv * A2;
        #pragma unroll
        for (int off = 1; off < 64; off <<= 1) {
            float o = __shfl_up(v, off, 64);
            if (lane >= off) v += o;
        }
        ct2l[h * 68 + lane] = v;
    }
    __syncthreads();

    // phase D split: group 0 -> G (full n); group 1 -> CS (full n)
    float G_[4][4] = {}, CS_[4][4] = {};
    if (grp == 0) {
        for (int n = 0; n < 64; n++) {
            float4 cr4 = *(const float4*)&Cy[XSW4(n, t4)];
            float4 br4 = *(const float4*)&Bz[XSW4(n, x4)];
            float cr[4] = {cr4.x, cr4.y, cr4.z, cr4.w};
            float br[4] = {br4.x, br4.y, br4.z, br4.w};
            #pragma unroll
            for (int r = 0; r < 4; r++)
                #pragma unroll
                for (int q = 0; q < 4; q++)
                    G_[r][q] += cr[r] * br[q];
        }
    } else {
        for (int n = 0; n < 64; n++) {
            float4 cr4 = *(const float4*)&Cy[XSW4(n, t4)];
            float cr[4] = {cr4.x, cr4.y, cr4.z, cr4.w};
            float sn[4];
            #pragma unroll
            for (int q = 0; q < 4; q++) sn[q] = SinT[n * 65 + 4 * x4 + q];
            #pragma unroll
            for (int r = 0; r < 4; r++)
                #pragma unroll
                for (int q = 0; q < 4; q++)
                    CS_[r][q] += cr[r] * sn[q];
        }
    }
    __syncthreads();  // B, C, Sin dead

    // exchange write: G -> Cy [k][257]; CS halves (x4<8) -> SinT [k][129]
    if (grp == 0) {
        #pragma unroll
        for (int k = 0; k < 16; k++) Cy[k * 257 + tg] = G_[k >> 2][k & 3];
    } else if (x4 < 8) {
        const int idx = t4 * 8 + x4;
        #pragma unroll
        for (int k = 0; k < 16; k++) SinT[k * 129 + idx] = CS_[k >> 2][k & 3];
    }
    __syncthreads();
    // exchange read
    if (grp == 1) {
        #pragma unroll
        for (int k = 0; k < 16; k++) G_[k >> 2][k & 3] = Cy[k * 257 + tg];
    } else if (x4 < 8) {
        const int idx = t4 * 8 + x4;
        #pragma unroll
        for (int k = 0; k < 16; k++) CS_[k >> 2][k & 3] = SinT[k * 129 + idx];
    }

    // phase E: proj z (cols 0..63) into Bz; WoN into uW
    for (int i = 0; i < 8; i++) {
        const int col = wv * 8 + i;
        const float* wp = Win + (size_t)(dir * 272 + col) * 16;
        float acc = 0.f;
        #pragma unroll
        for (int k = 0; k < 16; k++) acc += u[k] * wp[k];
        Bz[XSW(col, lane)] = acc;
    }
    for (int j = tid; j < 1024; j += 512) {
        int c = j >> 6, d = j & 63;
        uW[c * 65 + d] = Wout[dir * 1024 + j] * normw[dir * 64 + d];
    }
    __syncthreads();  // all G/CS reads done; Cy becomes yv

    // phase F: group g handles heads 8g..8g+7; results -> yv
    float* yv = Cy;  // [64 rows][4 p][17]
    const int tbase = 4 * t4;
    #pragma unroll 1
    for (int hh = 0; hh < 8; hh++) {
        const int h = 8 * grp + hh;
        const float* ctp = &ct2l[h * 68];
        const float* dtp = &dts[h * 68];
        float4 ctt4 = *(const float4*)&ctp[tbase];
        const float ctt[4] = {ctt4.x, ctt4.y, ctt4.z, ctt4.w};
        float ect[4];
        #pragma unroll
        for (int r = 0; r < 4; r++) ect[r] = __builtin_amdgcn_exp2f(ctt[r]);
        float4 cs4 = *(const float4*)&ctp[4 * x4];
        float4 dt4 = *(const float4*)&dtp[4 * x4];
        float v[16] = {0.f, 0.f, 0.f, 0.f, 0.f, 0.f, 0.f, 0.f,
                       0.f, 0.f, 0.f, 0.f, 0.f, 0.f, 0.f, 0.f};
        #pragma unroll
        for (int q = 0; q < 4; q++) {
            const int s = 4 * x4 + q;
            float csq = (q == 0) ? cs4.x : (q == 1) ? cs4.y : (q == 2) ? cs4.z : cs4.w;
            float dtq = (q == 0) ? dt4.x : (q == 1) ? dt4.y : (q == 2) ? dt4.z : dt4.w;
            float xv[4];
            #pragma unroll
            for (int p = 0; p < 4; p++) {
                int m = 4 * h + p;
                xv[p] = xh_c[m * 64 + (((x4 ^ (m & 15)) & 15) << 2) + q];
            }
            // direct exp2 per (r,q): kept entries have ctt[r]-csq <= 0 (no
            // overflow); masked entries may produce inf but the select drops
            // them before any inf*0 can form.
            #pragma unroll
            for (int r = 0; r < 4; r++) {
                float e = __builtin_amdgcn_exp2f(ctt[r] - csq);
                float w = (s <= tbase + r) ? (G_[r][q] * dtq) * e : 0.f;
                #pragma unroll
                for (int p = 0; p < 4; p++) v[4 * r + p] += w * xv[p];
            }
        }
        if (x4 == h) {
            #pragma unroll
            for (int r = 0; r < 4; r++)
                #pragma unroll
                for (int p = 0; p < 4; p++)
                    v[4 * r + p] += ect[r] * CS_[r][p];
        }
        // butterfly reduce-scatter over 16 lanes: lane x4 ends with S[x4]
        #pragma unroll
        for (int j = 0; j < 8; j++) {
            float a = (x4 & 8) ? v[j + 8] : v[j];
            float s_ = (x4 & 8) ? v[j] : v[j + 8];
            v[j] = a + __shfl_xor(s_, 8);
        }
        #pragma unroll
        for (int j = 0; j < 4; j++) {
            float a = (x4 & 4) ? v[j + 4] : v[j];
            float s_ = (x4 & 4) ? v[j] : v[j + 4];
            v[j] = a + __shfl_xor(s_, 4);
        }
        #pragma unroll
        for (int j = 0; j < 2; j++) {
            float a = (x4 & 2) ? v[j + 2] : v[j];
            float s_ = (x4 & 2) ? v[j] : v[j + 2];
            v[j] = a + __shfl_xor(s_, 2);
        }
        {
            float a = (x4 & 1) ? v[1] : v[0];
            float s_ = (x4 & 1) ? v[0] : v[1];
            v[0] = a + __shfl_xor(s_, 1);
        }
        const int row = tbase + (x4 >> 2);
        yv[(row * 4 + (x4 & 3)) * 17 + h] = v[0];
    }
    __syncthreads();

    // phase G: epilogue on tid<256: lane = (row = tid>>2, p = tid&3)
    float os[4];
    const int row = tid >> 2;
    const int p = tid & 3;
    if (tid < 256) {
        float gg[16], sumsq = 0.f;
        #pragma unroll
        for (int h = 0; h < 16; h++) {
            float yval = yv[(row * 4 + p) * 17 + h];
            int m = 4 * h + p;
            int ax = m * 64 + ((((row >> 2) ^ (m & 15)) & 15) << 2) + (row & 3);
            float xh = xh_c[ax];
            float zv = Bz[ax];
            float val = (yval + Dps[h] * xh) * fast_silu(zv);
            gg[h] = val;
            sumsq += val * val;
        }
        sumsq += __shfl_xor(sumsq, 1);
        sumsq += __shfl_xor(sumsq, 2);
        float rms = rsqrtf(sumsq * (1.f / 64.f) + 1e-5f);

        float oc[16];
        #pragma unroll
        for (int c = 0; c < 16; c++) {
            float a = 0.f;
            #pragma unroll
            for (int h = 0; h < 16; h++) a += gg[h] * uW[c * 65 + 4 * h + p];
            oc[c] = a;
        }
        #pragma unroll
        for (int c = 0; c < 16; c++) {
            oc[c] += __shfl_xor(oc[c], 1);
            oc[c] += __shfl_xor(oc[c], 2);
        }
        #pragma unroll
        for (int i2 = 0; i2 < 4; i2++) {
            float a0 = (p == 0) ? oc[i2] : oc[4 + i2];
            float a1 = (p == 2) ? oc[8 + i2] : oc[12 + i2];
            os[i2] = (((p & 2) == 0) ? a0 : a1) * rms;
        }
        size_t bl = (size_t)(b * 8192 + l0 + row);
        *(float4*)(ys + bl * 16 + 4 * p) = make_float4(os[0], os[1], os[2], os[3]);

        // BN partials
        float bs[4], bq[4];
        #pragma unroll
        for (int i2 = 0; i2 < 4; i2++) {
            float vv = fmaxf(os[i2], 0.f);
            bs[i2] = vv;
            bq[i2] = vv * vv;
        }
        #pragma unroll
        for (int off = 4; off < 64; off <<= 1) {
            #pragma unroll
            for (int i2 = 0; i2 < 4; i2++) {
                bs[i2] += __shfl_xor(bs[i2], off);
                bq[i2] += __shfl_xor(bq[i2], off);
            }
        }
        const int wlane = tid & 63, wvid = tid >> 6;
        if (wlane < 4) {
            #pragma unroll
            for (int i2 = 0; i2 < 4; i2++) {
                red[wvid][4 * wlane + i2] = bs[i2];
                red[wvid][16 + 4 * wlane + i2] = bq[i2];
            }
        }
    }
    __syncthreads();
    if (tid < 32) {
        float a = red[0][tid] + red[1][tid] + red[2][tid] + red[3][tid];
        partials[((size_t)(b * 128 + ck)) * 32 + tid] = a;
    }
}

// ---------------------------------------------------------------------------
// K_POOL_BN: reduce partials -> BN coefs, then BN + linear + maxpool(32).
// ---------------------------------------------------------------------------
__global__ __launch_bounds__(256) void k_pool_bn(
    const float* __restrict__ gamma, const float* __restrict__ beta,
    const float* __restrict__ lin_w, const float* __restrict__ lin_b,
    float* __restrict__ ws, float* __restrict__ out, int dir0, int dslm)
{
    float* base = ws + (size_t)(dslm * blockIdx.z) * PD;
    const float* ys = base + OFF_YS;
    const float* partials = base + OFF_PART;
    const int dir = dir0 + blockIdx.z;
    const int tid = threadIdx.x;
    __shared__ float red[8][33];
    __shared__ float cf[18];
    {
        int c = tid & 31, ks = tid >> 5;
        float a = 0.f;
        for (int k = ks * 128; k < ks * 128 + 128; k++) a += partials[k * 32 + c];
        red[ks][c] = a;
    }
    __syncthreads();
    if (tid < 32) {
        float a = 0.f;
        #pragma unroll
        for (int s2 = 1; s2 < 8; s2++) a += red[s2][tid];
        red[0][tid] += a;
    }
    __syncthreads();
    if (tid == 0) {
        float off = lin_b[dir];
        for (int c = 0; c < 16; c++) {
            float mu = red[0][c] * (1.f / 65536.f);
            float var = red[0][16 + c] * (1.f / 65536.f) - mu * mu;
            float inv = rsqrtf(var + 1e-5f);
            float coef = inv * gamma[dir * 16 + c] * lin_w[dir * 16 + c];
            cf[c] = coef;
            off += beta[dir * 16 + c] * lin_w[dir * 16 + c] - mu * coef;
        }
        cf[16] = off;
    }
    __syncthreads();

    const int b = blockIdx.x >> 3;
    const int jg = blockIdx.x & 7;
    const int j = jg * 32 + (tid >> 3);
    const int sub = tid & 7;
    float m = -3.4e38f;
    #pragma unroll
    for (int r = 0; r < 4; r++) {
        int l = j * PW + 8 * r + sub;
        const float* rowp = ys + (size_t)(b * 8192 + l) * 16;
        float sv = cf[16];
        #pragma unroll
        for (int k = 0; k < 4; k++) {
            float4 v4 = *(const float4*)(rowp + 4 * k);
            sv += fmaxf(v4.x, 0.f) * cf[4 * k] + fmaxf(v4.y, 0.f) * cf[4 * k + 1]
                + fmaxf(v4.z, 0.f) * cf[4 * k + 2] + fmaxf(v4.w, 0.f) * cf[4 * k + 3];
        }
        m = fmaxf(m, sv);
    }
    m = fmaxf(m, __shfl_xor(m, 1));
    m = fmaxf(m, __shfl_xor(m, 2));
    m = fmaxf(m, __shfl_xor(m, 4));
    if (sub == 0) out[b * 768 + dir * 256 + j] = m;
}

// ---------------------------------------------------------------------------
extern "C" void kernel_launch(void* const* d_in, const int* in_sizes, int n_in,
                              void* d_out, int out_size, void* d_ws, size_t ws_size,
                              hipStream_t stream) {
    const float* x     = (const float*)d_in[0];
    const float* Win   = (const float*)d_in[1];
    const float* convw = (const float*)d_in[2];
    const float* convb = (const float*)d_in[3];
    const float* dtb   = (const float*)d_in[4];
    const float* Alog  = (const float*)d_in[5];
    const float* Dp    = (const float*)d_in[6];
    const float* normw = (const float*)d_in[7];
    const float* Wout  = (const float*)d_in[8];
    const float* gamma = (const float*)d_in[9];
    const float* beta  = (const float*)d_in[10];
    const float* linw  = (const float*)d_in[11];
    const float* linb  = (const float*)d_in[12];
    float* out = (float*)d_out;
    float* ws = (float*)d_ws;

    const bool batched = ws_size >= (size_t)3 * PD * 4;
    const int nz = batched ? 3 : 1;
    const int dslm = batched ? 1 : 0;
    const int nloop = batched ? 1 : 3;

    for (int d0 = 0; d0 < nloop; ++d0) {
        k_delta<<<dim3(128, 8, nz), dim3(512), 0, stream>>>(
            x, Win, convw, convb, dtb, Alog, ws, d0, dslm);
        k_chunk_scan<<<dim3(512, 1, nz), dim3(64), 0, stream>>>(ws, dslm);
        k_out_epi<<<dim3(128, 8, nz), dim3(512), 0, stream>>>(
            x, Win, convw, convb, dtb, Alog, Dp, normw, Wout, ws, d0, dslm);
        k_pool_bn<<<dim3(64, 1, nz), dim3(256), 0, stream>>>(
            gamma, beta, linw, linb, ws, out, d0, dslm);
    }
}